// Round 3
// baseline (1316.726 us; speedup 1.0000x reference)
//
#include <hip/hip_runtime.h>
#include <hip/hip_bf16.h>

typedef __bf16 bf16_t;
typedef bf16_t bf16x8 __attribute__((ext_vector_type(8)));
typedef float f32x4 __attribute__((ext_vector_type(4)));

#define TOK 8192          // B*S
#define DMODEL 2048
#define DINNER 4096
#define XBCN 4352         // conv dim = 34*128
#define DSTATE 128
#define NH 64
#define HD 64
#define NBC 64            // B * (S/CHUNK) = 2*32
#define WINT_ROWS 8448    // z (4096) + xbc (4352)

// async global->LDS, 16B per lane, LDS dest = wave-uniform base + lane*16
__device__ __forceinline__ void gld16(const bf16_t* g, bf16_t* l) {
  __builtin_amdgcn_global_load_lds((const __attribute__((address_space(1))) void*)g,
                                   (__attribute__((address_space(3))) void*)l, 16, 0, 0);
}

// ---------------- utility kernels ----------------

// hidden f32 -> hi (bf16) + lo (bf16 residual)
__global__ __launch_bounds__(256)
void cast_split_kernel(const float* __restrict__ in, bf16_t* __restrict__ hi,
                       bf16_t* __restrict__ lo, size_t n) {
  size_t i = ((size_t)blockIdx.x * 256 + threadIdx.x) * 8;
  if (i + 8 > n) return;
  float4 a = *(const float4*)(in + i);
  float4 b = *(const float4*)(in + i + 4);
  float v[8] = {a.x,a.y,a.z,a.w,b.x,b.y,b.z,b.w};
  bf16x8 h, l;
#pragma unroll
  for (int j = 0; j < 8; ++j) {
    h[j] = (bf16_t)v[j];
    l[j] = (bf16_t)(v[j] - (float)h[j]);
  }
  *(bf16x8*)(hi + i) = h;
  *(bf16x8*)(lo + i) = l;
}

// in: R x C f32 row-major -> out: outRows x R bf16 (out[c][r] = in[r][c])
__global__ __launch_bounds__(256)
void transpose_cast_kernel(const float* __restrict__ in, bf16_t* __restrict__ out,
                           int R, int C, int outRows) {
  __shared__ float tile[32][33];
  const int c0 = blockIdx.x * 32;
  const int r0 = blockIdx.y * 32;
  const int tx = threadIdx.x & 31;
  const int ty = threadIdx.x >> 5;
#pragma unroll
  for (int k = 0; k < 4; ++k) {
    int r = r0 + ty + k*8;
    int c = c0 + tx;
    tile[ty + k*8][tx] = (c < C) ? in[(size_t)r * C + c] : 0.f;
  }
  __syncthreads();
#pragma unroll
  for (int k = 0; k < 4; ++k) {
    int oc = c0 + ty + k*8;
    int orr = r0 + tx;
    out[(size_t)oc * R + orr] = (bf16_t)tile[tx][ty + k*8];
  }
}

// W_in dt columns -> Whi/Wlo [64][2048] bf16 split
__global__ __launch_bounds__(256)
void wdt_split_kernel(const float* __restrict__ Win, bf16_t* __restrict__ Whi,
                      bf16_t* __restrict__ Wlo) {
  const int h = threadIdx.x & 63;
  const int k0 = blockIdx.x * 256 + (threadIdx.x >> 6) * 64;
#pragma unroll 4
  for (int i = 0; i < 64; ++i) {
    int k = k0 + i;
    float v = Win[(size_t)k * 8512 + 8448 + h];
    bf16_t hv = (bf16_t)v;
    Whi[(size_t)h * DMODEL + k] = hv;
    Wlo[(size_t)h * DMODEL + k] = (bf16_t)(v - (float)hv);
  }
}

// ---------------- main GEMM (m97 structure): A(MxK) @ B(NxK)^T -> C(MxN) ----------------
template <typename OutT>
__global__ __launch_bounds__(256, 2)
void gemm_bf16_tn(const bf16_t* __restrict__ A, const bf16_t* __restrict__ B,
                  OutT* __restrict__ C, int M, int N, int K) {
  __shared__ bf16_t sA[4096];   // [group(8)][lane(64)][e(8)] = rows 0..127 x k 0..31
  __shared__ bf16_t sB[4096];
  const int tid = threadIdx.x;
  const int lane = tid & 63;
  const int w = tid >> 6;
  const int wr = w >> 1, wc = w & 1;
  const long bm = (long)blockIdx.y * 128;
  const long bn = (long)blockIdx.x * 128;
  const int rlo = lane & 15;
  const int kq = lane >> 4;

  const bf16_t* Ag0 = A + (bm + 2*w*16 + rlo) * (long)K + kq*8;
  const bf16_t* Ag1 = Ag0 + 16*(long)K;
  const bf16_t* Bg0 = B + (bn + 2*w*16 + rlo) * (long)K + kq*8;
  const bf16_t* Bg1 = Bg0 + 16*(long)K;
  bf16_t* lA0 = &sA[(2*w)*512];
  bf16_t* lA1 = &sA[(2*w+1)*512];
  bf16_t* lB0 = &sB[(2*w)*512];
  bf16_t* lB1 = &sB[(2*w+1)*512];

  f32x4 acc[4][4] = {};

  for (int kt = 0; kt < K; kt += 32) {
    __syncthreads();
    gld16(Ag0 + kt, lA0);
    gld16(Ag1 + kt, lA1);
    gld16(Bg0 + kt, lB0);
    gld16(Bg1 + kt, lB1);
    __syncthreads();
    bf16x8 aF[4], bF[4];
#pragma unroll
    for (int i = 0; i < 4; ++i) aF[i] = *(const bf16x8*)&sA[((wr*4 + i)*64 + lane)*8];
#pragma unroll
    for (int i = 0; i < 4; ++i) bF[i] = *(const bf16x8*)&sB[((wc*4 + i)*64 + lane)*8];
#pragma unroll
    for (int mi = 0; mi < 4; ++mi)
#pragma unroll
      for (int ni = 0; ni < 4; ++ni)
        acc[mi][ni] = __builtin_amdgcn_mfma_f32_16x16x32_bf16(aF[mi], bF[ni], acc[mi][ni], 0, 0, 0);
  }

  const int cr = (lane >> 4) * 4;
  const int cc = lane & 15;
#pragma unroll
  for (int mi = 0; mi < 4; ++mi) {
#pragma unroll
    for (int ni = 0; ni < 4; ++ni) {
      long row = bm + wr*64 + mi*16 + cr;
      long col = bn + wc*64 + ni*16 + cc;
      OutT* Cp = C + row * (long)N + col;
#pragma unroll
      for (int r = 0; r < 4; ++r) Cp[(long)r * N] = (OutT)acc[mi][ni][r];
    }
  }
}

// ---------------- dt via split-bf16 MFMA: hi*hi + hi*lo + lo*hi ----------------
__global__ __launch_bounds__(256)
void dt_mfma_kernel(const bf16_t* __restrict__ Ahi, const bf16_t* __restrict__ Alo,
                    const bf16_t* __restrict__ Whi, const bf16_t* __restrict__ Wlo,
                    float* __restrict__ dtraw) {
  __shared__ bf16_t sAh[4096], sAl[4096], sBh[2048], sBl[2048];
  const int tid = threadIdx.x;
  const int lane = tid & 63;
  const int w = tid >> 6;
  const long bm = (long)blockIdx.x * 128;
  const int rlo = lane & 15;
  const int kq = lane >> 4;

  const bf16_t* Ah0 = Ahi + (bm + 2*w*16 + rlo) * (long)DMODEL + kq*8;
  const bf16_t* Ah1 = Ah0 + 16*(long)DMODEL;
  const bf16_t* Al0 = Alo + (bm + 2*w*16 + rlo) * (long)DMODEL + kq*8;
  const bf16_t* Al1 = Al0 + 16*(long)DMODEL;
  const bf16_t* Bh0 = Whi + (w*16 + rlo) * (long)DMODEL + kq*8;
  const bf16_t* Bl0 = Wlo + (w*16 + rlo) * (long)DMODEL + kq*8;

  f32x4 acc[2][4] = {};

  for (int kt = 0; kt < DMODEL; kt += 32) {
    __syncthreads();
    gld16(Ah0 + kt, &sAh[(2*w)*512]);
    gld16(Ah1 + kt, &sAh[(2*w+1)*512]);
    gld16(Al0 + kt, &sAl[(2*w)*512]);
    gld16(Al1 + kt, &sAl[(2*w+1)*512]);
    gld16(Bh0 + kt, &sBh[w*512]);
    gld16(Bl0 + kt, &sBl[w*512]);
    __syncthreads();
    bf16x8 ah[2], al[2], bh[4], bl[4];
#pragma unroll
    for (int i = 0; i < 2; ++i) {
      ah[i] = *(const bf16x8*)&sAh[((2*w + i)*64 + lane)*8];
      al[i] = *(const bf16x8*)&sAl[((2*w + i)*64 + lane)*8];
    }
#pragma unroll
    for (int n = 0; n < 4; ++n) {
      bh[n] = *(const bf16x8*)&sBh[(n*64 + lane)*8];
      bl[n] = *(const bf16x8*)&sBl[(n*64 + lane)*8];
    }
#pragma unroll
    for (int mi = 0; mi < 2; ++mi)
#pragma unroll
      for (int n = 0; n < 4; ++n) {
        acc[mi][n] = __builtin_amdgcn_mfma_f32_16x16x32_bf16(ah[mi], bh[n], acc[mi][n], 0,0,0);
        acc[mi][n] = __builtin_amdgcn_mfma_f32_16x16x32_bf16(ah[mi], bl[n], acc[mi][n], 0,0,0);
        acc[mi][n] = __builtin_amdgcn_mfma_f32_16x16x32_bf16(al[mi], bh[n], acc[mi][n], 0,0,0);
      }
  }

  const int cr = (lane >> 4) * 4;
  const int cc = lane & 15;
#pragma unroll
  for (int mi = 0; mi < 2; ++mi)
#pragma unroll
    for (int n = 0; n < 4; ++n)
#pragma unroll
      for (int r = 0; r < 4; ++r)
        dtraw[(bm + 2*w*16 + mi*16 + cr + r) * 64 + n*16 + cc] = acc[mi][n][r];
}

// ---------------- causal conv1d (K=4) + SiLU, split x/B/C ----------------
__global__ __launch_bounds__(256)
void conv_kernel(const bf16_t* __restrict__ xbc, const float* __restrict__ cw,
                 const float* __restrict__ cb, bf16_t* __restrict__ xo,
                 bf16_t* __restrict__ Bout, bf16_t* __restrict__ Cout) {
  const int c = blockIdx.x * 256 + threadIdx.x;
  const int t0 = blockIdx.y * 8;
  const int bstart = (t0 >> 12) << 12;
  const float w0 = cw[c*4+0], w1 = cw[c*4+1], w2 = cw[c*4+2], w3 = cw[c*4+3];
  const float bias = cb[c];
  float in[11];
#pragma unroll
  for (int k = 0; k < 11; ++k) {
    int t = t0 - 3 + k;
    in[k] = (t >= bstart) ? (float)xbc[(size_t)t * XBCN + c] : 0.f;
  }
#pragma unroll
  for (int i = 0; i < 8; ++i) {
    float v = bias + w0*in[i] + w1*in[i+1] + w2*in[i+2] + w3*in[i+3];
    float s = v / (1.f + __expf(-v));
    int t = t0 + i;
    bf16_t o = (bf16_t)s;
    if (c < DINNER)           xo[(size_t)t * DINNER + c] = o;
    else if (c < DINNER+128)  Bout[(size_t)t * DSTATE + (c - DINNER)] = o;
    else                      Cout[(size_t)t * DSTATE + (c - DINNER - 128)] = o;
  }
}

// ---------------- softplus(dt)+cumsum(dA) per (b,chunk,head) ----------------
__global__ __launch_bounds__(256)
void dt_scan_kernel(const float* __restrict__ dtraw, const float* __restrict__ dt_bias,
                    const float* __restrict__ Avec, float* __restrict__ dt_s,
                    float* __restrict__ dAcs, float* __restrict__ cdec) {
  const int wid = blockIdx.x * 4 + (threadIdx.x >> 6);
  const int lane = threadIdx.x & 63;
  const int h = wid & 63;
  const int bc = wid >> 6;
  const long tok0 = (long)bc * 128;
  const float Ah = Avec[h];
  const float bias = dt_bias[h];
  float v0 = dtraw[(tok0 + lane)*64 + h] + bias;
  float v1 = dtraw[(tok0 + 64 + lane)*64 + h] + bias;
  float d0 = (v0 > 20.f) ? v0 : log1pf(expf(v0));
  float d1 = (v1 > 20.f) ? v1 : log1pf(expf(v1));
  float s0 = d0 * Ah;
  float s1 = d1 * Ah;
#pragma unroll
  for (int off = 1; off < 64; off <<= 1) {
    float t = __shfl_up(s0, off);
    if (lane >= off) s0 += t;
  }
  float tot0 = __shfl(s0, 63);
#pragma unroll
  for (int off = 1; off < 64; off <<= 1) {
    float t = __shfl_up(s1, off);
    if (lane >= off) s1 += t;
  }
  s1 += tot0;
  const size_t base = (size_t)wid * 128;
  dt_s[base + lane] = d0;
  dt_s[base + 64 + lane] = d1;
  dAcs[base + lane] = s0;
  dAcs[base + 64 + lane] = s1;
  if (lane == 63) cdec[wid] = __expf(s1);
}

// ---------------- per-chunk states: dtx^T @ (decay .* Bm) -> (64 x 128) bf16 ----------------
__global__ __launch_bounds__(256)
void states_kernel(const bf16_t* __restrict__ x, const bf16_t* __restrict__ Bm,
                   const float* __restrict__ dt_s, const float* __restrict__ dAcs,
                   bf16_t* __restrict__ states) {
  __shared__ bf16_t sDtx[8192];
  __shared__ bf16_t sBd[16384];
  __shared__ float sDt[128];
  __shared__ float sDec[128];
  const int wid = blockIdx.x;
  const int h = wid & 63;
  const int bc = wid >> 6;
  const int tid = threadIdx.x;
  const int lane = tid & 63;
  const int w = tid >> 6;
  const long tok0 = (long)bc * 128;
  const size_t dbase = (size_t)wid * 128;

  if (tid < 128) {
    sDt[tid] = dt_s[dbase + tid];
  } else {
    int j = tid - 128;
    sDec[j] = __expf(dAcs[dbase + 127] - dAcs[dbase + j]);
  }
  __syncthreads();

  {
    const int jj0 = tid >> 3;
    const int pg = (tid & 7) * 8;
#pragma unroll
    for (int t = 0; t < 4; ++t) {
      int j = t*32 + jj0;
      bf16x8 xv = *(const bf16x8*)&x[(tok0 + j)*(long)DINNER + h*64 + pg];
      float dtj = sDt[j];
      int kq = (j >> 5) * 4;
      int qe = ((j >> 3) & 3) * 16;
      int e = j & 7;
#pragma unroll
      for (int i = 0; i < 8; ++i) {
        int p = pg + i;
        sDtx[((kq + (p>>4))*64 + qe + (p&15))*8 + e] = (bf16_t)((float)xv[i]*dtj);
      }
    }
    const int jj1 = tid >> 4;
    const int ng = (tid & 15) * 8;
#pragma unroll
    for (int t = 0; t < 8; ++t) {
      int j = t*16 + jj1;
      bf16x8 bv = *(const bf16x8*)&Bm[(tok0 + j)*(long)DSTATE + ng];
      float dec = sDec[j];
      int kq = (j >> 5) * 8;
      int qe = ((j >> 3) & 3) * 16;
      int e = j & 7;
#pragma unroll
      for (int i = 0; i < 8; ++i) {
        int n = ng + i;
        sBd[((kq + (n>>4))*64 + qe + (n&15))*8 + e] = (bf16_t)((float)bv[i]*dec);
      }
    }
  }
  __syncthreads();

  f32x4 acc[4][2] = {};
#pragma unroll
  for (int kt = 0; kt < 4; ++kt) {
    bf16x8 aF[4], bF[2];
#pragma unroll
    for (int mt = 0; mt < 4; ++mt) aF[mt] = *(const bf16x8*)&sDtx[((kt*4 + mt)*64 + lane)*8];
#pragma unroll
    for (int nt = 0; nt < 2; ++nt) bF[nt] = *(const bf16x8*)&sBd[((kt*8 + w*2 + nt)*64 + lane)*8];
#pragma unroll
    for (int mt = 0; mt < 4; ++mt)
#pragma unroll
      for (int nt = 0; nt < 2; ++nt)
        acc[mt][nt] = __builtin_amdgcn_mfma_f32_16x16x32_bf16(aF[mt], bF[nt], acc[mt][nt], 0,0,0);
  }

  bf16_t* S = states + (size_t)wid * (HD * DSTATE);
  const int cr = (lane >> 4) * 4;
  const int cc = lane & 15;
#pragma unroll
  for (int mt = 0; mt < 4; ++mt)
#pragma unroll
    for (int nt = 0; nt < 2; ++nt) {
      int n = (w*2 + nt)*16 + cc;
#pragma unroll
      for (int r = 0; r < 4; ++r) {
        int p = mt*16 + cr + r;
        S[(size_t)p*DSTATE + n] = (bf16_t)acc[mt][nt][r];
      }
    }
}

// ---------------- inter-chunk scan over 32 chunks (in-place: states -> prevs) ----------------
__global__ __launch_bounds__(256)
void scan_kernel(bf16_t* __restrict__ sp, const float* __restrict__ cdec) {
  const size_t gid = (size_t)blockIdx.x * 256 + threadIdx.x;
  const int n = gid & 127;
  const int p = (gid >> 7) & 63;
  const int h = (gid >> 13) & 63;
  const int b = (int)(gid >> 19);
  float prev = 0.f;
  const size_t pn = (size_t)p * 128 + n;
  for (int c = 0; c < 32; ++c) {
    const int wid = (b*32 + c)*64 + h;
    const size_t idx = (size_t)wid * 8192 + pn;
    float s = (float)sp[idx];
    sp[idx] = (bf16_t)prev;
    prev = cdec[wid] * prev + s;
  }
}

// ---------------- per-chunk Y: inter + intra + D*x (in-place over x) ----------------
__global__ __launch_bounds__(256)
void ssd_y_kernel(bf16_t* __restrict__ xy, const bf16_t* __restrict__ Bm,
                  const bf16_t* __restrict__ Cm, const bf16_t* __restrict__ prevs,
                  const float* __restrict__ dt_s, const float* __restrict__ dAcs,
                  const float* __restrict__ Dvec) {
  __shared__ bf16_t sG[16384];
  __shared__ bf16_t sDtx[8192];
  __shared__ float sDA[128];
  __shared__ float sEA[128];
  __shared__ float sDt[128];

  const int wid = blockIdx.x;
  const int h = wid & 63;
  const int bc = wid >> 6;
  const int tid = threadIdx.x;
  const int lane = tid & 63;
  const int w = tid >> 6;
  const long tok0 = (long)bc * 128;
  const size_t dbase = (size_t)wid * 128;

  if (tid < 128) {
    float v = dAcs[dbase + tid];
    sDA[tid] = v;
    sEA[tid] = __expf(v);
  } else {
    sDt[tid - 128] = dt_s[dbase + tid - 128];
  }
  __syncthreads();

  {
    const int jj0 = tid >> 3;
    const int pg = (tid & 7) * 8;
#pragma unroll
    for (int t = 0; t < 4; ++t) {
      int j = t*32 + jj0;
      bf16x8 xv = *(const bf16x8*)&xy[(tok0 + j)*(long)DINNER + h*64 + pg];
      float dtj = sDt[j];
      int kq = (j >> 5) * 4;
      int qe = ((j >> 3) & 3) * 16;
      int e = j & 7;
#pragma unroll
      for (int i = 0; i < 8; ++i) {
        int p = pg + i;
        sDtx[((kq + (p>>4))*64 + qe + (p&15))*8 + e] = (bf16_t)((float)xv[i]*dtj);
      }
    }
  }

  const int arow = (w*2)*16 + (lane & 15);
  const int koff = (lane >> 4) * 8;
  bf16x8 aCm[2][4];
#pragma unroll
  for (int mi = 0; mi < 2; ++mi)
#pragma unroll
    for (int kt = 0; kt < 4; ++kt)
      aCm[mi][kt] = *(const bf16x8*)&Cm[(tok0 + arow + mi*16)*(long)DSTATE + kt*32 + koff];

  const bf16_t* P = prevs + (size_t)wid * 8192;
  f32x4 accY[2][4] = {};
#pragma unroll
  for (int kt = 0; kt < 4; ++kt) {
    bf16x8 bP[4];
#pragma unroll
    for (int ni = 0; ni < 4; ++ni)
      bP[ni] = *(const bf16x8*)&P[(size_t)(ni*16 + (lane & 15))*DSTATE + kt*32 + koff];
#pragma unroll
    for (int mi = 0; mi < 2; ++mi)
#pragma unroll
      for (int ni = 0; ni < 4; ++ni)
        accY[mi][ni] = __builtin_amdgcn_mfma_f32_16x16x32_bf16(aCm[mi][kt], bP[ni], accY[mi][ni], 0,0,0);
  }
  const int cr = (lane >> 4) * 4;
  const int cc = lane & 15;
#pragma unroll
  for (int mi = 0; mi < 2; ++mi)
#pragma unroll
    for (int r = 0; r < 4; ++r) {
      float e = sEA[(w*2 + mi)*16 + cr + r];
#pragma unroll
      for (int ni = 0; ni < 4; ++ni) accY[mi][ni][r] *= e;
    }

  f32x4 accS[2][8] = {};
#pragma unroll
  for (int kt = 0; kt < 4; ++kt) {
    bf16x8 bB[8];
#pragma unroll
    for (int nt = 0; nt < 8; ++nt)
      bB[nt] = *(const bf16x8*)&Bm[(tok0 + nt*16 + (lane & 15))*(long)DSTATE + kt*32 + koff];
#pragma unroll
    for (int mi = 0; mi < 2; ++mi)
#pragma unroll
      for (int nt = 0; nt < 8; ++nt)
        accS[mi][nt] = __builtin_amdgcn_mfma_f32_16x16x32_bf16(aCm[mi][kt], bB[nt], accS[mi][nt], 0,0,0);
  }

#pragma unroll
  for (int mi = 0; mi < 2; ++mi)
#pragma unroll
    for (int nt = 0; nt < 8; ++nt)
#pragma unroll
      for (int r = 0; r < 4; ++r) {
        int i = (w*2 + mi)*16 + cr + r;
        int j = nt*16 + cc;
        float g = (i >= j) ? accS[mi][nt][r] * __expf(sDA[i] - sDA[j]) : 0.f;
        sG[(((j>>5)*8 + (i>>4))*64 + ((j>>3)&3)*16 + (i&15))*8 + (j&7)] = (bf16_t)g;
      }
  __syncthreads();

#pragma unroll
  for (int kt = 0; kt < 4; ++kt) {
    bf16x8 aG[2], bD[4];
#pragma unroll
    for (int mi = 0; mi < 2; ++mi) aG[mi] = *(const bf16x8*)&sG[((kt*8 + w*2 + mi)*64 + lane)*8];
#pragma unroll
    for (int ni = 0; ni < 4; ++ni) bD[ni] = *(const bf16x8*)&sDtx[((kt*4 + ni)*64 + lane)*8];
#pragma unroll
    for (int mi = 0; mi < 2; ++mi)
#pragma unroll
      for (int ni = 0; ni < 4; ++ni)
        accY[mi][ni] = __builtin_amdgcn_mfma_f32_16x16x32_bf16(aG[mi], bD[ni], accY[mi][ni], 0,0,0);
  }

  const float Dh = Dvec[h];
#pragma unroll
  for (int mi = 0; mi < 2; ++mi)
#pragma unroll
    for (int ni = 0; ni < 4; ++ni)
#pragma unroll
      for (int r = 0; r < 4; ++r) {
        long tokr = tok0 + (w*2 + mi)*16 + cr + r;
        int p = ni*16 + cc;
        long idx = tokr * DINNER + h*64 + p;
        float xv = (float)xy[idx];
        xy[idx] = (bf16_t)(accY[mi][ni][r] + Dh * xv);
      }
}

// ---------------- gating + RMS norm ----------------
__global__ __launch_bounds__(256)
void gate_kernel(const bf16_t* __restrict__ y, const bf16_t* __restrict__ z,
                 const float* __restrict__ norm_w, bf16_t* __restrict__ yn) {
  const int tok = blockIdx.x;
  const int tid = threadIdx.x;
  const int lane = tid & 63;
  const int w = tid >> 6;
  const bf16_t* yrow = y + (size_t)tok * DINNER;
  const bf16_t* zrow = z + (size_t)tok * DINNER;
  float local[16];
  float ss = 0.f;
#pragma unroll
  for (int v = 0; v < 2; ++v) {
    int col = tid*16 + v*8;
    bf16x8 yv = *(const bf16x8*)&yrow[col];
    bf16x8 zv = *(const bf16x8*)&zrow[col];
#pragma unroll
    for (int i = 0; i < 8; ++i) {
      float zf = (float)zv[i];
      float g = zf / (1.f + __expf(-zf));
      float t = (float)yv[i] * g;
      local[v*8 + i] = t;
      ss += t*t;
    }
  }
#pragma unroll
  for (int off = 32; off > 0; off >>= 1) ss += __shfl_xor(ss, off);
  __shared__ float red[4];
  if (lane == 0) red[w] = ss;
  __syncthreads();
  float rms = rsqrtf((red[0]+red[1]+red[2]+red[3]) * (1.f/DINNER) + 1e-5f);
  bf16_t* orow = yn + (size_t)tok * DINNER;
#pragma unroll
  for (int v = 0; v < 2; ++v) {
    int col = tid*16 + v*8;
    bf16x8 o;
#pragma unroll
    for (int i = 0; i < 8; ++i) o[i] = (bf16_t)(local[v*8+i] * rms * norm_w[col+i]);
    *(bf16x8*)&orow[col] = o;
  }
}

// ---------------- launch ----------------
extern "C" void kernel_launch(void* const* d_in, const int* in_sizes, int n_in,
                              void* d_out, int out_size, void* d_ws, size_t ws_size,
                              hipStream_t stream) {
  const float* hidden  = (const float*)d_in[0];
  const float* W_in    = (const float*)d_in[1];
  const float* conv_w  = (const float*)d_in[2];
  const float* conv_b  = (const float*)d_in[3];
  const float* Avec    = (const float*)d_in[4];
  const float* Dvec    = (const float*)d_in[5];
  const float* dt_bias = (const float*)d_in[6];
  const float* norm_w  = (const float*)d_in[7];
  const float* W_out   = (const float*)d_in[8];

  char* ws = (char*)d_ws;
  size_t off = 0;
  auto take = [&](size_t bytes) -> char* {
    char* p = ws + off;
    off += (bytes + 255) & ~(size_t)255;
    return p;
  };
  bf16_t* R1    = (bf16_t*)take((size_t)NBC * NH * HD * DSTATE * 2);  // Xb -> states -> ynbuf
  bf16_t* WinT  = (bf16_t*)take((size_t)WINT_ROWS * DMODEL * 2);      // later WoutT
  bf16_t* xbc   = (bf16_t*)take((size_t)TOK * XBCN * 2);              // Xlo lives here first
  bf16_t* xconv = (bf16_t*)take((size_t)TOK * DINNER * 2);            // y in-place
  bf16_t* Bmat  = (bf16_t*)take((size_t)TOK * DSTATE * 2);
  bf16_t* Cmat  = (bf16_t*)take((size_t)TOK * DSTATE * 2);
  float*  dtraw = (float*)take((size_t)TOK * NH * 4);
  float*  dt_s  = (float*)take((size_t)TOK * NH * 4);
  float*  dAcs  = (float*)take((size_t)TOK * NH * 4);
  float*  cdec  = (float*)take((size_t)NBC * NH * 4);
  bf16_t* Wdth  = (bf16_t*)take((size_t)NH * DMODEL * 2);
  bf16_t* Wdtl  = (bf16_t*)take((size_t)NH * DMODEL * 2);
  if (off > ws_size) return;

  bf16_t* Xb      = R1;
  bf16_t* Xlo     = xbc;               // dead before xbc-gemm writes
  bf16_t* statesB = R1;
  bf16_t* ynbuf   = R1;
  bf16_t* WoutT   = WinT;
  bf16_t* zbuf    = (bf16_t*)d_out;    // z as bf16 in d_out
  float*  out     = (float*)d_out;

  cast_split_kernel<<<(TOK*DMODEL)/2048, 256, 0, stream>>>(hidden, Xb, Xlo, (size_t)TOK*DMODEL);
  wdt_split_kernel<<<DMODEL/256, 256, 0, stream>>>(W_in, Wdth, Wdtl);
  dt_mfma_kernel<<<TOK/128, 256, 0, stream>>>(Xb, Xlo, Wdth, Wdtl, dtraw);
  transpose_cast_kernel<<<dim3(WINT_ROWS/32, DMODEL/32), 256, 0, stream>>>(W_in, WinT, DMODEL, 8512, WINT_ROWS);
  gemm_bf16_tn<bf16_t><<<dim3(DINNER/128, TOK/128), 256, 0, stream>>>(Xb, WinT, zbuf, TOK, DINNER, DMODEL);
  gemm_bf16_tn<bf16_t><<<dim3(XBCN/128, TOK/128), 256, 0, stream>>>(Xb, WinT + (size_t)DINNER*DMODEL, xbc, TOK, XBCN, DMODEL);
  transpose_cast_kernel<<<dim3(DMODEL/32, DINNER/32), 256, 0, stream>>>(W_out, WoutT, DINNER, DMODEL, DMODEL);
  conv_kernel<<<dim3(XBCN/256, TOK/8), 256, 0, stream>>>(xbc, conv_w, conv_b, xconv, Bmat, Cmat);
  dt_scan_kernel<<<(NBC*NH)/4, 256, 0, stream>>>(dtraw, dt_bias, Avec, dt_s, dAcs, cdec);
  states_kernel<<<NBC*NH, 256, 0, stream>>>(xconv, Bmat, dt_s, dAcs, statesB);
  scan_kernel<<<(NBC*NH*HD*DSTATE)/(32*256), 256, 0, stream>>>(statesB, cdec);
  ssd_y_kernel<<<NBC*NH, 256, 0, stream>>>(xconv, Bmat, Cmat, statesB, dt_s, dAcs, Dvec);
  gate_kernel<<<TOK, 256, 0, stream>>>(xconv, zbuf, norm_w, ynbuf);
  gemm_bf16_tn<float><<<dim3(DMODEL/128, TOK/128), 256, 0, stream>>>(ynbuf, WoutT, out, TOK, DMODEL, DINNER);
}

// Round 4
// 1312.572 us; speedup vs baseline: 1.0032x; 1.0032x over previous
//
#include <hip/hip_runtime.h>
#include <hip/hip_bf16.h>

typedef __bf16 bf16_t;
typedef bf16_t bf16x8 __attribute__((ext_vector_type(8)));
typedef float f32x4 __attribute__((ext_vector_type(4)));

#define TOK 8192          // B*S
#define DMODEL 2048
#define DINNER 4096
#define XBCN 4352         // conv dim = 34*128
#define DSTATE 128
#define NH 64
#define HD 64
#define NBC 64            // B * (S/CHUNK) = 2*32
#define WINT_ROWS 8448    // z (4096) + xbc (4352)

// async global->LDS, 16B per lane, LDS dest = wave-uniform base + lane*16
__device__ __forceinline__ void gld16(const bf16_t* g, bf16_t* l) {
  __builtin_amdgcn_global_load_lds((const __attribute__((address_space(1))) void*)g,
                                   (__attribute__((address_space(3))) void*)l, 16, 0, 0);
}

// ---------------- utility kernels ----------------

// hidden f32 -> hi (bf16) + lo (bf16 residual)
__global__ __launch_bounds__(256)
void cast_split_kernel(const float* __restrict__ in, bf16_t* __restrict__ hi,
                       bf16_t* __restrict__ lo, size_t n) {
  size_t i = ((size_t)blockIdx.x * 256 + threadIdx.x) * 8;
  if (i + 8 > n) return;
  float4 a = *(const float4*)(in + i);
  float4 b = *(const float4*)(in + i + 4);
  float v[8] = {a.x,a.y,a.z,a.w,b.x,b.y,b.z,b.w};
  bf16x8 h, l;
#pragma unroll
  for (int j = 0; j < 8; ++j) {
    h[j] = (bf16_t)v[j];
    l[j] = (bf16_t)(v[j] - (float)h[j]);
  }
  *(bf16x8*)(hi + i) = h;
  *(bf16x8*)(lo + i) = l;
}

// in: R x C f32 row-major -> out: outRows x R bf16 (out[c][r] = in[r][c])
__global__ __launch_bounds__(256)
void transpose_cast_kernel(const float* __restrict__ in, bf16_t* __restrict__ out,
                           int R, int C, int outRows) {
  __shared__ float tile[32][33];
  const int c0 = blockIdx.x * 32;
  const int r0 = blockIdx.y * 32;
  const int tx = threadIdx.x & 31;
  const int ty = threadIdx.x >> 5;
#pragma unroll
  for (int k = 0; k < 4; ++k) {
    int r = r0 + ty + k*8;
    int c = c0 + tx;
    tile[ty + k*8][tx] = (c < C) ? in[(size_t)r * C + c] : 0.f;
  }
  __syncthreads();
#pragma unroll
  for (int k = 0; k < 4; ++k) {
    int oc = c0 + ty + k*8;
    int orr = r0 + tx;
    out[(size_t)oc * R + orr] = (bf16_t)tile[tx][ty + k*8];
  }
}

// W_in dt columns -> Whi/Wlo [64][2048] bf16 split
__global__ __launch_bounds__(256)
void wdt_split_kernel(const float* __restrict__ Win, bf16_t* __restrict__ Whi,
                      bf16_t* __restrict__ Wlo) {
  const int h = threadIdx.x & 63;
  const int k0 = blockIdx.x * 256 + (threadIdx.x >> 6) * 64;
#pragma unroll 4
  for (int i = 0; i < 64; ++i) {
    int k = k0 + i;
    float v = Win[(size_t)k * 8512 + 8448 + h];
    bf16_t hv = (bf16_t)v;
    Whi[(size_t)h * DMODEL + k] = hv;
    Wlo[(size_t)h * DMODEL + k] = (bf16_t)(v - (float)hv);
  }
}

// ---------------- main GEMM: 2-phase double-buffered global_load_lds ----------------
// A(MxK) @ B(NxK)^T -> C(MxN). 1D grid with bijective XCD swizzle (nwg%8==0).
template <typename OutT>
__global__ __launch_bounds__(256, 2)
void gemm_bf16_tn(const bf16_t* __restrict__ A, const bf16_t* __restrict__ B,
                  OutT* __restrict__ C, int M, int N, int K, int gridX) {
  __shared__ bf16_t sA[2][4096];   // [buf][group(8)][lane(64)][e(8)]
  __shared__ bf16_t sB[2][4096];
  const int tid = threadIdx.x;
  const int lane = tid & 63;
  const int w = tid >> 6;
  const int wr = w >> 1, wc = w & 1;

  // XCD-aware swizzle: XCD k gets logical tiles [k*nwg/8, (k+1)*nwg/8)
  const int nwg = gridDim.x;
  const int cpx = nwg >> 3;
  const int swz = (blockIdx.x & 7) * cpx + (blockIdx.x >> 3);
  const long bm = (long)(swz / gridX) * 128;
  const long bn = (long)(swz % gridX) * 128;

  const int rlo = lane & 15;
  const int kq = lane >> 4;

  const bf16_t* Ag0 = A + (bm + 2*w*16 + rlo) * (long)K + kq*8;
  const bf16_t* Ag1 = Ag0 + 16*(long)K;
  const bf16_t* Bg0 = B + (bn + 2*w*16 + rlo) * (long)K + kq*8;
  const bf16_t* Bg1 = Bg0 + 16*(long)K;

  f32x4 acc[4][4] = {};

  auto stage = [&](int buf, int kt) {
    gld16(Ag0 + kt, &sA[buf][(2*w)*512]);
    gld16(Ag1 + kt, &sA[buf][(2*w+1)*512]);
    gld16(Bg0 + kt, &sB[buf][(2*w)*512]);
    gld16(Bg1 + kt, &sB[buf][(2*w+1)*512]);
  };
  auto compute = [&](int buf) {
    bf16x8 aF[4], bF[4];
#pragma unroll
    for (int i = 0; i < 4; ++i) aF[i] = *(const bf16x8*)&sA[buf][((wr*4 + i)*64 + lane)*8];
#pragma unroll
    for (int i = 0; i < 4; ++i) bF[i] = *(const bf16x8*)&sB[buf][((wc*4 + i)*64 + lane)*8];
#pragma unroll
    for (int mi = 0; mi < 4; ++mi)
#pragma unroll
      for (int ni = 0; ni < 4; ++ni)
        acc[mi][ni] = __builtin_amdgcn_mfma_f32_16x16x32_bf16(aF[mi], bF[ni], acc[mi][ni], 0, 0, 0);
  };

  // prologue: fill buf0; __syncthreads() drains vmcnt(0) then barriers
  stage(0, 0);
  __syncthreads();
  int cur = 0;
  for (int kt = 32; kt < K; kt += 32) {
    stage(cur ^ 1, kt);   // issue next tile BEFORE compute: MFMA hides load latency
    compute(cur);
    __syncthreads();      // vmcnt(0)+lgkmcnt(0) drain + barrier
    cur ^= 1;
  }
  compute(cur);

  const int cr = (lane >> 4) * 4;
  const int cc = lane & 15;
#pragma unroll
  for (int mi = 0; mi < 4; ++mi) {
#pragma unroll
    for (int ni = 0; ni < 4; ++ni) {
      long row = bm + wr*64 + mi*16 + cr;
      long col = bn + wc*64 + ni*16 + cc;
      OutT* Cp = C + row * (long)N + col;
#pragma unroll
      for (int r = 0; r < 4; ++r) Cp[(long)r * N] = (OutT)acc[mi][ni][r];
    }
  }
}

// ---------------- dt via split-bf16 MFMA: hi*hi + hi*lo + lo*hi ----------------
__global__ __launch_bounds__(256)
void dt_mfma_kernel(const bf16_t* __restrict__ Ahi, const bf16_t* __restrict__ Alo,
                    const bf16_t* __restrict__ Whi, const bf16_t* __restrict__ Wlo,
                    float* __restrict__ dtraw) {
  __shared__ bf16_t sAh[4096], sAl[4096], sBh[2048], sBl[2048];
  const int tid = threadIdx.x;
  const int lane = tid & 63;
  const int w = tid >> 6;
  const long bm = (long)blockIdx.x * 128;
  const int rlo = lane & 15;
  const int kq = lane >> 4;

  const bf16_t* Ah0 = Ahi + (bm + 2*w*16 + rlo) * (long)DMODEL + kq*8;
  const bf16_t* Ah1 = Ah0 + 16*(long)DMODEL;
  const bf16_t* Al0 = Alo + (bm + 2*w*16 + rlo) * (long)DMODEL + kq*8;
  const bf16_t* Al1 = Al0 + 16*(long)DMODEL;
  const bf16_t* Bh0 = Whi + (w*16 + rlo) * (long)DMODEL + kq*8;
  const bf16_t* Bl0 = Wlo + (w*16 + rlo) * (long)DMODEL + kq*8;

  f32x4 acc[2][4] = {};

  for (int kt = 0; kt < DMODEL; kt += 32) {
    __syncthreads();
    gld16(Ah0 + kt, &sAh[(2*w)*512]);
    gld16(Ah1 + kt, &sAh[(2*w+1)*512]);
    gld16(Al0 + kt, &sAl[(2*w)*512]);
    gld16(Al1 + kt, &sAl[(2*w+1)*512]);
    gld16(Bh0 + kt, &sBh[w*512]);
    gld16(Bl0 + kt, &sBl[w*512]);
    __syncthreads();
    bf16x8 ah[2], al[2], bh[4], bl[4];
#pragma unroll
    for (int i = 0; i < 2; ++i) {
      ah[i] = *(const bf16x8*)&sAh[((2*w + i)*64 + lane)*8];
      al[i] = *(const bf16x8*)&sAl[((2*w + i)*64 + lane)*8];
    }
#pragma unroll
    for (int n = 0; n < 4; ++n) {
      bh[n] = *(const bf16x8*)&sBh[(n*64 + lane)*8];
      bl[n] = *(const bf16x8*)&sBl[(n*64 + lane)*8];
    }
#pragma unroll
    for (int mi = 0; mi < 2; ++mi)
#pragma unroll
      for (int n = 0; n < 4; ++n) {
        acc[mi][n] = __builtin_amdgcn_mfma_f32_16x16x32_bf16(ah[mi], bh[n], acc[mi][n], 0,0,0);
        acc[mi][n] = __builtin_amdgcn_mfma_f32_16x16x32_bf16(ah[mi], bl[n], acc[mi][n], 0,0,0);
        acc[mi][n] = __builtin_amdgcn_mfma_f32_16x16x32_bf16(al[mi], bh[n], acc[mi][n], 0,0,0);
      }
  }

  const int cr = (lane >> 4) * 4;
  const int cc = lane & 15;
#pragma unroll
  for (int mi = 0; mi < 2; ++mi)
#pragma unroll
    for (int n = 0; n < 4; ++n)
#pragma unroll
      for (int r = 0; r < 4; ++r)
        dtraw[(bm + 2*w*16 + mi*16 + cr + r) * 64 + n*16 + cc] = acc[mi][n][r];
}

// ---------------- causal conv1d (K=4) + SiLU, split x/B/C ----------------
__global__ __launch_bounds__(256)
void conv_kernel(const bf16_t* __restrict__ xbc, const float* __restrict__ cw,
                 const float* __restrict__ cb, bf16_t* __restrict__ xo,
                 bf16_t* __restrict__ Bout, bf16_t* __restrict__ Cout) {
  const int c = blockIdx.x * 256 + threadIdx.x;
  const int t0 = blockIdx.y * 8;
  const int bstart = (t0 >> 12) << 12;
  const float w0 = cw[c*4+0], w1 = cw[c*4+1], w2 = cw[c*4+2], w3 = cw[c*4+3];
  const float bias = cb[c];
  float in[11];
#pragma unroll
  for (int k = 0; k < 11; ++k) {
    int t = t0 - 3 + k;
    in[k] = (t >= bstart) ? (float)xbc[(size_t)t * XBCN + c] : 0.f;
  }
#pragma unroll
  for (int i = 0; i < 8; ++i) {
    float v = bias + w0*in[i] + w1*in[i+1] + w2*in[i+2] + w3*in[i+3];
    float s = v / (1.f + __expf(-v));
    int t = t0 + i;
    bf16_t o = (bf16_t)s;
    if (c < DINNER)           xo[(size_t)t * DINNER + c] = o;
    else if (c < DINNER+128)  Bout[(size_t)t * DSTATE + (c - DINNER)] = o;
    else                      Cout[(size_t)t * DSTATE + (c - DINNER - 128)] = o;
  }
}

// ---------------- softplus(dt)+cumsum(dA) per (b,chunk,head) ----------------
__global__ __launch_bounds__(256)
void dt_scan_kernel(const float* __restrict__ dtraw, const float* __restrict__ dt_bias,
                    const float* __restrict__ Avec, float* __restrict__ dt_s,
                    float* __restrict__ dAcs, float* __restrict__ cdec) {
  const int wid = blockIdx.x * 4 + (threadIdx.x >> 6);
  const int lane = threadIdx.x & 63;
  const int h = wid & 63;
  const int bc = wid >> 6;
  const long tok0 = (long)bc * 128;
  const float Ah = Avec[h];
  const float bias = dt_bias[h];
  float v0 = dtraw[(tok0 + lane)*64 + h] + bias;
  float v1 = dtraw[(tok0 + 64 + lane)*64 + h] + bias;
  float d0 = (v0 > 20.f) ? v0 : log1pf(expf(v0));
  float d1 = (v1 > 20.f) ? v1 : log1pf(expf(v1));
  float s0 = d0 * Ah;
  float s1 = d1 * Ah;
#pragma unroll
  for (int off = 1; off < 64; off <<= 1) {
    float t = __shfl_up(s0, off);
    if (lane >= off) s0 += t;
  }
  float tot0 = __shfl(s0, 63);
#pragma unroll
  for (int off = 1; off < 64; off <<= 1) {
    float t = __shfl_up(s1, off);
    if (lane >= off) s1 += t;
  }
  s1 += tot0;
  const size_t base = (size_t)wid * 128;
  dt_s[base + lane] = d0;
  dt_s[base + 64 + lane] = d1;
  dAcs[base + lane] = s0;
  dAcs[base + 64 + lane] = s1;
  if (lane == 63) cdec[wid] = __expf(s1);
}

// ---------------- per-chunk states: dtx^T @ (decay .* Bm) -> (64 x 128) bf16 ----------------
__global__ __launch_bounds__(256)
void states_kernel(const bf16_t* __restrict__ x, const bf16_t* __restrict__ Bm,
                   const float* __restrict__ dt_s, const float* __restrict__ dAcs,
                   bf16_t* __restrict__ states) {
  __shared__ bf16_t sDtx[8192];
  __shared__ bf16_t sBd[16384];
  __shared__ float sDt[128];
  __shared__ float sDec[128];
  const int wid = blockIdx.x;
  const int h = wid & 63;
  const int bc = wid >> 6;
  const int tid = threadIdx.x;
  const int lane = tid & 63;
  const int w = tid >> 6;
  const long tok0 = (long)bc * 128;
  const size_t dbase = (size_t)wid * 128;

  if (tid < 128) {
    sDt[tid] = dt_s[dbase + tid];
  } else {
    int j = tid - 128;
    sDec[j] = __expf(dAcs[dbase + 127] - dAcs[dbase + j]);
  }
  __syncthreads();

  {
    const int jj0 = tid >> 3;
    const int pg = (tid & 7) * 8;
#pragma unroll
    for (int t = 0; t < 4; ++t) {
      int j = t*32 + jj0;
      bf16x8 xv = *(const bf16x8*)&x[(tok0 + j)*(long)DINNER + h*64 + pg];
      float dtj = sDt[j];
      int kq = (j >> 5) * 4;
      int qe = ((j >> 3) & 3) * 16;
      int e = j & 7;
#pragma unroll
      for (int i = 0; i < 8; ++i) {
        int p = pg + i;
        sDtx[((kq + (p>>4))*64 + qe + (p&15))*8 + e] = (bf16_t)((float)xv[i]*dtj);
      }
    }
    const int jj1 = tid >> 4;
    const int ng = (tid & 15) * 8;
#pragma unroll
    for (int t = 0; t < 8; ++t) {
      int j = t*16 + jj1;
      bf16x8 bv = *(const bf16x8*)&Bm[(tok0 + j)*(long)DSTATE + ng];
      float dec = sDec[j];
      int kq = (j >> 5) * 8;
      int qe = ((j >> 3) & 3) * 16;
      int e = j & 7;
#pragma unroll
      for (int i = 0; i < 8; ++i) {
        int n = ng + i;
        sBd[((kq + (n>>4))*64 + qe + (n&15))*8 + e] = (bf16_t)((float)bv[i]*dec);
      }
    }
  }
  __syncthreads();

  f32x4 acc[4][2] = {};
#pragma unroll
  for (int kt = 0; kt < 4; ++kt) {
    bf16x8 aF[4], bF[2];
#pragma unroll
    for (int mt = 0; mt < 4; ++mt) aF[mt] = *(const bf16x8*)&sDtx[((kt*4 + mt)*64 + lane)*8];
#pragma unroll
    for (int nt = 0; nt < 2; ++nt) bF[nt] = *(const bf16x8*)&sBd[((kt*8 + w*2 + nt)*64 + lane)*8];
#pragma unroll
    for (int mt = 0; mt < 4; ++mt)
#pragma unroll
      for (int nt = 0; nt < 2; ++nt)
        acc[mt][nt] = __builtin_amdgcn_mfma_f32_16x16x32_bf16(aF[mt], bF[nt], acc[mt][nt], 0,0,0);
  }

  bf16_t* S = states + (size_t)wid * (HD * DSTATE);
  const int cr = (lane >> 4) * 4;
  const int cc = lane & 15;
#pragma unroll
  for (int mt = 0; mt < 4; ++mt)
#pragma unroll
    for (int nt = 0; nt < 2; ++nt) {
      int n = (w*2 + nt)*16 + cc;
#pragma unroll
      for (int r = 0; r < 4; ++r) {
        int p = mt*16 + cr + r;
        S[(size_t)p*DSTATE + n] = (bf16_t)acc[mt][nt][r];
      }
    }
}

// ---------------- inter-chunk scan over 32 chunks (in-place: states -> prevs) ----------------
__global__ __launch_bounds__(256)
void scan_kernel(bf16_t* __restrict__ sp, const float* __restrict__ cdec) {
  const size_t gid = (size_t)blockIdx.x * 256 + threadIdx.x;
  const int n = gid & 127;
  const int p = (gid >> 7) & 63;
  const int h = (gid >> 13) & 63;
  const int b = (int)(gid >> 19);
  float prev = 0.f;
  const size_t pn = (size_t)p * 128 + n;
  for (int c = 0; c < 32; ++c) {
    const int wid = (b*32 + c)*64 + h;
    const size_t idx = (size_t)wid * 8192 + pn;
    float s = (float)sp[idx];
    sp[idx] = (bf16_t)prev;
    prev = cdec[wid] * prev + s;
  }
}

// ---------------- per-chunk Y: inter + intra + D*x (in-place over x) ----------------
__global__ __launch_bounds__(256)
void ssd_y_kernel(bf16_t* __restrict__ xy, const bf16_t* __restrict__ Bm,
                  const bf16_t* __restrict__ Cm, const bf16_t* __restrict__ prevs,
                  const float* __restrict__ dt_s, const float* __restrict__ dAcs,
                  const float* __restrict__ Dvec) {
  __shared__ bf16_t sG[16384];
  __shared__ bf16_t sDtx[8192];
  __shared__ float sDA[128];
  __shared__ float sEA[128];
  __shared__ float sDt[128];

  const int wid = blockIdx.x;
  const int h = wid & 63;
  const int bc = wid >> 6;
  const int tid = threadIdx.x;
  const int lane = tid & 63;
  const int w = tid >> 6;
  const long tok0 = (long)bc * 128;
  const size_t dbase = (size_t)wid * 128;

  if (tid < 128) {
    float v = dAcs[dbase + tid];
    sDA[tid] = v;
    sEA[tid] = __expf(v);
  } else {
    sDt[tid - 128] = dt_s[dbase + tid - 128];
  }
  __syncthreads();

  {
    const int jj0 = tid >> 3;
    const int pg = (tid & 7) * 8;
#pragma unroll
    for (int t = 0; t < 4; ++t) {
      int j = t*32 + jj0;
      bf16x8 xv = *(const bf16x8*)&xy[(tok0 + j)*(long)DINNER + h*64 + pg];
      float dtj = sDt[j];
      int kq = (j >> 5) * 4;
      int qe = ((j >> 3) & 3) * 16;
      int e = j & 7;
#pragma unroll
      for (int i = 0; i < 8; ++i) {
        int p = pg + i;
        sDtx[((kq + (p>>4))*64 + qe + (p&15))*8 + e] = (bf16_t)((float)xv[i]*dtj);
      }
    }
  }

  const int arow = (w*2)*16 + (lane & 15);
  const int koff = (lane >> 4) * 8;
  bf16x8 aCm[2][4];
#pragma unroll
  for (int mi = 0; mi < 2; ++mi)
#pragma unroll
    for (int kt = 0; kt < 4; ++kt)
      aCm[mi][kt] = *(const bf16x8*)&Cm[(tok0 + arow + mi*16)*(long)DSTATE + kt*32 + koff];

  const bf16_t* P = prevs + (size_t)wid * 8192;
  f32x4 accY[2][4] = {};
#pragma unroll
  for (int kt = 0; kt < 4; ++kt) {
    bf16x8 bP[4];
#pragma unroll
    for (int ni = 0; ni < 4; ++ni)
      bP[ni] = *(const bf16x8*)&P[(size_t)(ni*16 + (lane & 15))*DSTATE + kt*32 + koff];
#pragma unroll
    for (int mi = 0; mi < 2; ++mi)
#pragma unroll
      for (int ni = 0; ni < 4; ++ni)
        accY[mi][ni] = __builtin_amdgcn_mfma_f32_16x16x32_bf16(aCm[mi][kt], bP[ni], accY[mi][ni], 0,0,0);
  }
  const int cr = (lane >> 4) * 4;
  const int cc = lane & 15;
#pragma unroll
  for (int mi = 0; mi < 2; ++mi)
#pragma unroll
    for (int r = 0; r < 4; ++r) {
      float e = sEA[(w*2 + mi)*16 + cr + r];
#pragma unroll
      for (int ni = 0; ni < 4; ++ni) accY[mi][ni][r] *= e;
    }

  f32x4 accS[2][8] = {};
#pragma unroll
  for (int kt = 0; kt < 4; ++kt) {
    bf16x8 bB[8];
#pragma unroll
    for (int nt = 0; nt < 8; ++nt)
      bB[nt] = *(const bf16x8*)&Bm[(tok0 + nt*16 + (lane & 15))*(long)DSTATE + kt*32 + koff];
#pragma unroll
    for (int mi = 0; mi < 2; ++mi)
#pragma unroll
      for (int nt = 0; nt < 8; ++nt)
        accS[mi][nt] = __builtin_amdgcn_mfma_f32_16x16x32_bf16(aCm[mi][kt], bB[nt], accS[mi][nt], 0,0,0);
  }

#pragma unroll
  for (int mi = 0; mi < 2; ++mi)
#pragma unroll
    for (int nt = 0; nt < 8; ++nt)
#pragma unroll
      for (int r = 0; r < 4; ++r) {
        int i = (w*2 + mi)*16 + cr + r;
        int j = nt*16 + cc;
        float g = (i >= j) ? accS[mi][nt][r] * __expf(sDA[i] - sDA[j]) : 0.f;
        sG[(((j>>5)*8 + (i>>4))*64 + ((j>>3)&3)*16 + (i&15))*8 + (j&7)] = (bf16_t)g;
      }
  __syncthreads();

#pragma unroll
  for (int kt = 0; kt < 4; ++kt) {
    bf16x8 aG[2], bD[4];
#pragma unroll
    for (int mi = 0; mi < 2; ++mi) aG[mi] = *(const bf16x8*)&sG[((kt*8 + w*2 + mi)*64 + lane)*8];
#pragma unroll
    for (int ni = 0; ni < 4; ++ni) bD[ni] = *(const bf16x8*)&sDtx[((kt*4 + ni)*64 + lane)*8];
#pragma unroll
    for (int mi = 0; mi < 2; ++mi)
#pragma unroll
      for (int ni = 0; ni < 4; ++ni)
        accY[mi][ni] = __builtin_amdgcn_mfma_f32_16x16x32_bf16(aG[mi], bD[ni], accY[mi][ni], 0,0,0);
  }

  const float Dh = Dvec[h];
#pragma unroll
  for (int mi = 0; mi < 2; ++mi)
#pragma unroll
    for (int ni = 0; ni < 4; ++ni)
#pragma unroll
      for (int r = 0; r < 4; ++r) {
        long tokr = tok0 + (w*2 + mi)*16 + cr + r;
        int p = ni*16 + cc;
        long idx = tokr * DINNER + h*64 + p;
        float xv = (float)xy[idx];
        xy[idx] = (bf16_t)(accY[mi][ni][r] + Dh * xv);
      }
}

// ---------------- gating + RMS norm ----------------
__global__ __launch_bounds__(256)
void gate_kernel(const bf16_t* __restrict__ y, const bf16_t* __restrict__ z,
                 const float* __restrict__ norm_w, bf16_t* __restrict__ yn) {
  const int tok = blockIdx.x;
  const int tid = threadIdx.x;
  const int lane = tid & 63;
  const int w = tid >> 6;
  const bf16_t* yrow = y + (size_t)tok * DINNER;
  const bf16_t* zrow = z + (size_t)tok * DINNER;
  float local[16];
  float ss = 0.f;
#pragma unroll
  for (int v = 0; v < 2; ++v) {
    int col = tid*16 + v*8;
    bf16x8 yv = *(const bf16x8*)&yrow[col];
    bf16x8 zv = *(const bf16x8*)&zrow[col];
#pragma unroll
    for (int i = 0; i < 8; ++i) {
      float zf = (float)zv[i];
      float g = zf / (1.f + __expf(-zf));
      float t = (float)yv[i] * g;
      local[v*8 + i] = t;
      ss += t*t;
    }
  }
#pragma unroll
  for (int off = 32; off > 0; off >>= 1) ss += __shfl_xor(ss, off);
  __shared__ float red[4];
  if (lane == 0) red[w] = ss;
  __syncthreads();
  float rms = rsqrtf((red[0]+red[1]+red[2]+red[3]) * (1.f/DINNER) + 1e-5f);
  bf16_t* orow = yn + (size_t)tok * DINNER;
#pragma unroll
  for (int v = 0; v < 2; ++v) {
    int col = tid*16 + v*8;
    bf16x8 o;
#pragma unroll
    for (int i = 0; i < 8; ++i) o[i] = (bf16_t)(local[v*8+i] * rms * norm_w[col+i]);
    *(bf16x8*)&orow[col] = o;
  }
}

// ---------------- launch ----------------
extern "C" void kernel_launch(void* const* d_in, const int* in_sizes, int n_in,
                              void* d_out, int out_size, void* d_ws, size_t ws_size,
                              hipStream_t stream) {
  const float* hidden  = (const float*)d_in[0];
  const float* W_in    = (const float*)d_in[1];
  const float* conv_w  = (const float*)d_in[2];
  const float* conv_b  = (const float*)d_in[3];
  const float* Avec    = (const float*)d_in[4];
  const float* Dvec    = (const float*)d_in[5];
  const float* dt_bias = (const float*)d_in[6];
  const float* norm_w  = (const float*)d_in[7];
  const float* W_out   = (const float*)d_in[8];

  char* ws = (char*)d_ws;
  size_t off = 0;
  auto take = [&](size_t bytes) -> char* {
    char* p = ws + off;
    off += (bytes + 255) & ~(size_t)255;
    return p;
  };
  bf16_t* R1    = (bf16_t*)take((size_t)NBC * NH * HD * DSTATE * 2);  // Xb -> states -> ynbuf
  bf16_t* WinT  = (bf16_t*)take((size_t)WINT_ROWS * DMODEL * 2);      // later WoutT
  bf16_t* xbc   = (bf16_t*)take((size_t)TOK * XBCN * 2);              // Xlo lives here first
  bf16_t* xconv = (bf16_t*)take((size_t)TOK * DINNER * 2);            // y in-place
  bf16_t* Bmat  = (bf16_t*)take((size_t)TOK * DSTATE * 2);
  bf16_t* Cmat  = (bf16_t*)take((size_t)TOK * DSTATE * 2);
  float*  dtraw = (float*)take((size_t)TOK * NH * 4);
  float*  dt_s  = (float*)take((size_t)TOK * NH * 4);
  float*  dAcs  = (float*)take((size_t)TOK * NH * 4);
  float*  cdec  = (float*)take((size_t)NBC * NH * 4);
  bf16_t* Wdth  = (bf16_t*)take((size_t)NH * DMODEL * 2);
  bf16_t* Wdtl  = (bf16_t*)take((size_t)NH * DMODEL * 2);
  if (off > ws_size) return;

  bf16_t* Xb      = R1;
  bf16_t* Xlo     = xbc;               // dead before xbc-gemm writes
  bf16_t* statesB = R1;
  bf16_t* ynbuf   = R1;
  bf16_t* WoutT   = WinT;
  bf16_t* zbuf    = (bf16_t*)d_out;    // z as bf16 in d_out
  float*  out     = (float*)d_out;

  cast_split_kernel<<<(TOK*DMODEL)/2048, 256, 0, stream>>>(hidden, Xb, Xlo, (size_t)TOK*DMODEL);
  wdt_split_kernel<<<DMODEL/256, 256, 0, stream>>>(W_in, Wdth, Wdtl);
  dt_mfma_kernel<<<TOK/128, 256, 0, stream>>>(Xb, Xlo, Wdth, Wdtl, dtraw);
  transpose_cast_kernel<<<dim3(WINT_ROWS/32, DMODEL/32), 256, 0, stream>>>(W_in, WinT, DMODEL, 8512, WINT_ROWS);
  gemm_bf16_tn<bf16_t><<<(DINNER/128)*(TOK/128), 256, 0, stream>>>(Xb, WinT, zbuf, TOK, DINNER, DMODEL, DINNER/128);
  gemm_bf16_tn<bf16_t><<<(XBCN/128)*(TOK/128), 256, 0, stream>>>(Xb, WinT + (size_t)DINNER*DMODEL, xbc, TOK, XBCN, DMODEL, XBCN/128);
  transpose_cast_kernel<<<dim3(DMODEL/32, DINNER/32), 256, 0, stream>>>(W_out, WoutT, DINNER, DMODEL, DMODEL);
  conv_kernel<<<dim3(XBCN/256, TOK/8), 256, 0, stream>>>(xbc, conv_w, conv_b, xconv, Bmat, Cmat);
  dt_scan_kernel<<<(NBC*NH)/4, 256, 0, stream>>>(dtraw, dt_bias, Avec, dt_s, dAcs, cdec);
  states_kernel<<<NBC*NH, 256, 0, stream>>>(xconv, Bmat, dt_s, dAcs, statesB);
  scan_kernel<<<(NBC*NH*HD*DSTATE)/(32*256), 256, 0, stream>>>(statesB, cdec);
  ssd_y_kernel<<<NBC*NH, 256, 0, stream>>>(xconv, Bmat, Cmat, statesB, dt_s, dAcs, Dvec);
  gate_kernel<<<TOK, 256, 0, stream>>>(xconv, zbuf, norm_w, ynbuf);
  gemm_bf16_tn<float><<<(DMODEL/128)*(TOK/128), 256, 0, stream>>>(ynbuf, WoutT, out, TOK, DMODEL, DINNER, DMODEL/128);
}

// Round 5
// 1089.868 us; speedup vs baseline: 1.2082x; 1.2043x over previous
//
#include <hip/hip_runtime.h>
#include <hip/hip_bf16.h>

typedef __bf16 bf16_t;
typedef bf16_t bf16x8 __attribute__((ext_vector_type(8)));
typedef float f32x4 __attribute__((ext_vector_type(4)));

#define TOK 8192          // B*S
#define DMODEL 2048
#define DINNER 4096
#define XBCN 4352         // conv dim = 34*128
#define DSTATE 128
#define NH 64
#define HD 64
#define NBC 64            // B * (S/CHUNK) = 2*32
#define WINT_ROWS 8448    // z (4096) + xbc (4352)

// async global->LDS, 16B per lane, LDS dest = wave-uniform base + lane*16
__device__ __forceinline__ void gld16(const bf16_t* g, bf16_t* l) {
  __builtin_amdgcn_global_load_lds((const __attribute__((address_space(1))) void*)g,
                                   (__attribute__((address_space(3))) void*)l, 16, 0, 0);
}

__device__ __forceinline__ f32x4 mfma16(bf16x8 a, bf16x8 b, f32x4 c) {
  return __builtin_amdgcn_mfma_f32_16x16x32_bf16(a, b, c, 0, 0, 0);
}

// ---------------- utility kernels ----------------

// hidden f32 -> hi (bf16) + lo (bf16 residual)
__global__ __launch_bounds__(256)
void cast_split_kernel(const float* __restrict__ in, bf16_t* __restrict__ hi,
                       bf16_t* __restrict__ lo, size_t n) {
  size_t i = ((size_t)blockIdx.x * 256 + threadIdx.x) * 8;
  if (i + 8 > n) return;
  float4 a = *(const float4*)(in + i);
  float4 b = *(const float4*)(in + i + 4);
  float v[8] = {a.x,a.y,a.z,a.w,b.x,b.y,b.z,b.w};
  bf16x8 h, l;
#pragma unroll
  for (int j = 0; j < 8; ++j) {
    h[j] = (bf16_t)v[j];
    l[j] = (bf16_t)(v[j] - (float)h[j]);
  }
  *(bf16x8*)(hi + i) = h;
  *(bf16x8*)(lo + i) = l;
}

// in: R x C f32 row-major -> out: outRows x R bf16 (out[c][r] = in[r][c])
__global__ __launch_bounds__(256)
void transpose_cast_kernel(const float* __restrict__ in, bf16_t* __restrict__ out,
                           int R, int C, int outRows) {
  __shared__ float tile[32][33];
  const int c0 = blockIdx.x * 32;
  const int r0 = blockIdx.y * 32;
  const int tx = threadIdx.x & 31;
  const int ty = threadIdx.x >> 5;
#pragma unroll
  for (int k = 0; k < 4; ++k) {
    int r = r0 + ty + k*8;
    int c = c0 + tx;
    tile[ty + k*8][tx] = (c < C) ? in[(size_t)r * C + c] : 0.f;
  }
  __syncthreads();
#pragma unroll
  for (int k = 0; k < 4; ++k) {
    int oc = c0 + ty + k*8;
    int orr = r0 + tx;
    out[(size_t)oc * R + orr] = (bf16_t)tile[tx][ty + k*8];
  }
}

// W_in dt columns -> Whi/Wlo [64][2048] bf16 split
__global__ __launch_bounds__(256)
void wdt_split_kernel(const float* __restrict__ Win, bf16_t* __restrict__ Whi,
                      bf16_t* __restrict__ Wlo) {
  const int h = threadIdx.x & 63;
  const int k0 = blockIdx.x * 256 + (threadIdx.x >> 6) * 64;
#pragma unroll 4
  for (int i = 0; i < 64; ++i) {
    int k = k0 + i;
    float v = Win[(size_t)k * 8512 + 8448 + h];
    bf16_t hv = (bf16_t)v;
    Whi[(size_t)h * DMODEL + k] = hv;
    Wlo[(size_t)h * DMODEL + k] = (bf16_t)(v - (float)hv);
  }
}

// ---------------- 256x256 8-phase GEMM: A(MxK) @ B(NxK)^T -> C(MxN) ----------------
// 512 threads = 8 waves (2M x 4N), BK=64, 128KB LDS double-buffered.
// LDS in MFMA-fragment order (pre-swizzled global source, linear LDS dest) ->
// conflict-free ds_read_b128 and gld16. Counted vmcnt (never 0 in steady loop).
// Optional column split: cols [0,splitN) -> C0 (ld=splitN), [splitN,N) -> C1.
template <typename OutT>
__global__ __launch_bounds__(512, 2)
void gemm256(const bf16_t* __restrict__ A, const bf16_t* __restrict__ B,
             OutT* __restrict__ C0, OutT* __restrict__ C1,
             long M, long N, long K, long splitN, int gridX) {
  __shared__ bf16_t sA[2][2][8192];   // [buf][half][(f*2+s)*512 + lane*8 + e]
  __shared__ bf16_t sB[2][2][8192];
  const int tid = threadIdx.x;
  const int lane = tid & 63;
  const int wid = tid >> 6;          // 0..7
  const int wr = wid >> 2;           // 0..1  (M)
  const int wc = wid & 3;            // 0..3  (N)

  // bijective XCD swizzle (grid % 8 == 0)
  const int nwg = gridDim.x;
  const int cpx = nwg >> 3;
  const int swz = (blockIdx.x & 7) * cpx + (blockIdx.x >> 3);
  const long bm = (long)(swz / gridX) * 256;
  const long bn = (long)(swz % gridX) * 256;

  // staging source mapping (fragment order): wave wid stages (f=wid>>1, s=wid&1)
  const int srow = (wid >> 1) * 16 + (lane & 15);      // + c*64 within 128-row half
  const int skof = (wid & 1) * 32 + (lane >> 4) * 8;   // k within 64-k tile
  const bf16_t* Abase = A + (bm + srow) * K + skof;
  const bf16_t* Bbase = B + (bn + srow) * K + skof;

  auto stageA = [&](int buf, int h, long kt) {
    const bf16_t* s = Abase + (long)h * 128 * K + kt;
    gld16(s,          &sA[buf][h][wid * 512]);
    gld16(s + 64 * K, &sA[buf][h][4096 + wid * 512]);
  };
  auto stageB = [&](int buf, int h, long kt) {
    const bf16_t* s = Bbase + (long)h * 128 * K + kt;
    gld16(s,          &sB[buf][h][wid * 512]);
    gld16(s + 64 * K, &sB[buf][h][4096 + wid * 512]);
  };
  auto rdA = [&](int buf, int h, int f, int s) -> bf16x8 {
    return *(const bf16x8*)&sA[buf][h][((f * 2 + s) * 64 + lane) * 8];
  };
  auto rdB = [&](int buf, int h, int f, int s) -> bf16x8 {
    return *(const bf16x8*)&sB[buf][h][((f * 2 + s) * 64 + lane) * 8];
  };

  // prologue: stage tile 0 in ledger order A0,B0,B1,A1
  stageA(0, 0, 0); stageB(0, 0, 0); stageB(0, 1, 0); stageA(0, 1, 0);

  f32x4 acc[8][4] = {};
  bf16x8 a[4][2], b[2][2];
  int cur = 0;
  const int NT = (int)(K >> 6);

  for (int t = 0; t < NT; ++t) {
    const bool fin = (t == NT - 1);
    const long ktn = (long)(t + 1) * 64;
    // ---- phase 0: A-half0 x B-half0 ----
    asm volatile("s_waitcnt vmcnt(4)\n\ts_barrier" ::: "memory");
#pragma unroll
    for (int mi = 0; mi < 4; ++mi) {
      a[mi][0] = rdA(cur, 0, wr*4 + mi, 0);
      a[mi][1] = rdA(cur, 0, wr*4 + mi, 1);
    }
#pragma unroll
    for (int ni = 0; ni < 2; ++ni) {
      b[ni][0] = rdB(cur, 0, wc*2 + ni, 0);
      b[ni][1] = rdB(cur, 0, wc*2 + ni, 1);
    }
    if (!fin) stageA(cur ^ 1, 0, ktn);
    __builtin_amdgcn_s_setprio(1);
#pragma unroll
    for (int mi = 0; mi < 4; ++mi)
#pragma unroll
      for (int ni = 0; ni < 2; ++ni) {
        acc[mi][ni] = mfma16(a[mi][0], b[ni][0], acc[mi][ni]);
        acc[mi][ni] = mfma16(a[mi][1], b[ni][1], acc[mi][ni]);
      }
    __builtin_amdgcn_s_setprio(0);
    // ---- phase 1: A-half0 x B-half1 ----
    if (!fin) asm volatile("s_waitcnt vmcnt(4)\n\ts_barrier" ::: "memory");
    else      asm volatile("s_waitcnt vmcnt(2)\n\ts_barrier" ::: "memory");
#pragma unroll
    for (int ni = 0; ni < 2; ++ni) {
      b[ni][0] = rdB(cur, 1, wc*2 + ni, 0);
      b[ni][1] = rdB(cur, 1, wc*2 + ni, 1);
    }
    if (!fin) stageB(cur ^ 1, 0, ktn);
    __builtin_amdgcn_s_setprio(1);
#pragma unroll
    for (int mi = 0; mi < 4; ++mi)
#pragma unroll
      for (int ni = 0; ni < 2; ++ni) {
        acc[mi][2 + ni] = mfma16(a[mi][0], b[ni][0], acc[mi][2 + ni]);
        acc[mi][2 + ni] = mfma16(a[mi][1], b[ni][1], acc[mi][2 + ni]);
      }
    __builtin_amdgcn_s_setprio(0);
    // ---- phase 2: A-half1 x B-half1 ----
    if (!fin) asm volatile("s_waitcnt vmcnt(4)\n\ts_barrier" ::: "memory");
    else      asm volatile("s_waitcnt vmcnt(0)\n\ts_barrier" ::: "memory");
#pragma unroll
    for (int mi = 0; mi < 4; ++mi) {
      a[mi][0] = rdA(cur, 1, wr*4 + mi, 0);
      a[mi][1] = rdA(cur, 1, wr*4 + mi, 1);
    }
    if (!fin) stageB(cur ^ 1, 1, ktn);
    __builtin_amdgcn_s_setprio(1);
#pragma unroll
    for (int mi = 0; mi < 4; ++mi)
#pragma unroll
      for (int ni = 0; ni < 2; ++ni) {
        acc[4 + mi][2 + ni] = mfma16(a[mi][0], b[ni][0], acc[4 + mi][2 + ni]);
        acc[4 + mi][2 + ni] = mfma16(a[mi][1], b[ni][1], acc[4 + mi][2 + ni]);
      }
    __builtin_amdgcn_s_setprio(0);
    // ---- phase 3: A-half1 x B-half0 (re-read B0 from LDS) ----
    asm volatile("s_barrier" ::: "memory");
#pragma unroll
    for (int ni = 0; ni < 2; ++ni) {
      b[ni][0] = rdB(cur, 0, wc*2 + ni, 0);
      b[ni][1] = rdB(cur, 0, wc*2 + ni, 1);
    }
    if (!fin) stageA(cur ^ 1, 1, ktn);
    __builtin_amdgcn_s_setprio(1);
#pragma unroll
    for (int mi = 0; mi < 4; ++mi)
#pragma unroll
      for (int ni = 0; ni < 2; ++ni) {
        acc[4 + mi][ni] = mfma16(a[mi][0], b[ni][0], acc[4 + mi][ni]);
        acc[4 + mi][ni] = mfma16(a[mi][1], b[ni][1], acc[4 + mi][ni]);
      }
    __builtin_amdgcn_s_setprio(0);
    cur ^= 1;
  }

  // epilogue
  const int cr = (lane >> 4) * 4;
  const int cc = lane & 15;
  OutT* Cb;
  long col0, ldc;
  if (bn < splitN) { Cb = C0; col0 = bn; ldc = splitN; }
  else             { Cb = C1; col0 = bn - splitN; ldc = N - splitN; }
#pragma unroll
  for (int mi = 0; mi < 8; ++mi) {
    long row = bm + (mi >> 2) * 128 + wr * 64 + (mi & 3) * 16 + cr;
#pragma unroll
    for (int ni = 0; ni < 4; ++ni) {
      long col = col0 + (ni >> 1) * 128 + wc * 32 + (ni & 1) * 16 + cc;
      OutT* p = Cb + row * ldc + col;
#pragma unroll
      for (int r = 0; r < 4; ++r) p[(long)r * ldc] = (OutT)acc[mi][ni][r];
    }
  }
}

// ---------------- dt via split-bf16 MFMA: hi*hi + hi*lo + lo*hi ----------------
__global__ __launch_bounds__(256)
void dt_mfma_kernel(const bf16_t* __restrict__ Ahi, const bf16_t* __restrict__ Alo,
                    const bf16_t* __restrict__ Whi, const bf16_t* __restrict__ Wlo,
                    float* __restrict__ dtraw) {
  __shared__ bf16_t sAh[4096], sAl[4096], sBh[2048], sBl[2048];
  const int tid = threadIdx.x;
  const int lane = tid & 63;
  const int w = tid >> 6;
  const long bm = (long)blockIdx.x * 128;
  const int rlo = lane & 15;
  const int kq = lane >> 4;

  const bf16_t* Ah0 = Ahi + (bm + 2*w*16 + rlo) * (long)DMODEL + kq*8;
  const bf16_t* Ah1 = Ah0 + 16*(long)DMODEL;
  const bf16_t* Al0 = Alo + (bm + 2*w*16 + rlo) * (long)DMODEL + kq*8;
  const bf16_t* Al1 = Al0 + 16*(long)DMODEL;
  const bf16_t* Bh0 = Whi + (w*16 + rlo) * (long)DMODEL + kq*8;
  const bf16_t* Bl0 = Wlo + (w*16 + rlo) * (long)DMODEL + kq*8;

  f32x4 acc[2][4] = {};

  for (int kt = 0; kt < DMODEL; kt += 32) {
    __syncthreads();
    gld16(Ah0 + kt, &sAh[(2*w)*512]);
    gld16(Ah1 + kt, &sAh[(2*w+1)*512]);
    gld16(Al0 + kt, &sAl[(2*w)*512]);
    gld16(Al1 + kt, &sAl[(2*w+1)*512]);
    gld16(Bh0 + kt, &sBh[w*512]);
    gld16(Bl0 + kt, &sBl[w*512]);
    __syncthreads();
    bf16x8 ah[2], al[2], bh[4], bl[4];
#pragma unroll
    for (int i = 0; i < 2; ++i) {
      ah[i] = *(const bf16x8*)&sAh[((2*w + i)*64 + lane)*8];
      al[i] = *(const bf16x8*)&sAl[((2*w + i)*64 + lane)*8];
    }
#pragma unroll
    for (int n = 0; n < 4; ++n) {
      bh[n] = *(const bf16x8*)&sBh[(n*64 + lane)*8];
      bl[n] = *(const bf16x8*)&sBl[(n*64 + lane)*8];
    }
#pragma unroll
    for (int mi = 0; mi < 2; ++mi)
#pragma unroll
      for (int n = 0; n < 4; ++n) {
        acc[mi][n] = mfma16(ah[mi], bh[n], acc[mi][n]);
        acc[mi][n] = mfma16(ah[mi], bl[n], acc[mi][n]);
        acc[mi][n] = mfma16(al[mi], bh[n], acc[mi][n]);
      }
  }

  const int cr = (lane >> 4) * 4;
  const int cc = lane & 15;
#pragma unroll
  for (int mi = 0; mi < 2; ++mi)
#pragma unroll
    for (int n = 0; n < 4; ++n)
#pragma unroll
      for (int r = 0; r < 4; ++r)
        dtraw[(bm + 2*w*16 + mi*16 + cr + r) * 64 + n*16 + cc] = acc[mi][n][r];
}

// ---------------- causal conv1d (K=4) + SiLU, split x/B/C ----------------
__global__ __launch_bounds__(256)
void conv_kernel(const bf16_t* __restrict__ xbc, const float* __restrict__ cw,
                 const float* __restrict__ cb, bf16_t* __restrict__ xo,
                 bf16_t* __restrict__ Bout, bf16_t* __restrict__ Cout) {
  const int c = blockIdx.x * 256 + threadIdx.x;
  const int t0 = blockIdx.y * 8;
  const int bstart = (t0 >> 12) << 12;
  const float w0 = cw[c*4+0], w1 = cw[c*4+1], w2 = cw[c*4+2], w3 = cw[c*4+3];
  const float bias = cb[c];
  float in[11];
#pragma unroll
  for (int k = 0; k < 11; ++k) {
    int t = t0 - 3 + k;
    in[k] = (t >= bstart) ? (float)xbc[(size_t)t * XBCN + c] : 0.f;
  }
#pragma unroll
  for (int i = 0; i < 8; ++i) {
    float v = bias + w0*in[i] + w1*in[i+1] + w2*in[i+2] + w3*in[i+3];
    float s = v / (1.f + __expf(-v));
    int t = t0 + i;
    bf16_t o = (bf16_t)s;
    if (c < DINNER)           xo[(size_t)t * DINNER + c] = o;
    else if (c < DINNER+128)  Bout[(size_t)t * DSTATE + (c - DINNER)] = o;
    else                      Cout[(size_t)t * DSTATE + (c - DINNER - 128)] = o;
  }
}

// ---------------- softplus(dt)+cumsum(dA) per (b,chunk,head) ----------------
__global__ __launch_bounds__(256)
void dt_scan_kernel(const float* __restrict__ dtraw, const float* __restrict__ dt_bias,
                    const float* __restrict__ Avec, float* __restrict__ dt_s,
                    float* __restrict__ dAcs, float* __restrict__ cdec) {
  const int wid = blockIdx.x * 4 + (threadIdx.x >> 6);
  const int lane = threadIdx.x & 63;
  const int h = wid & 63;
  const int bc = wid >> 6;
  const long tok0 = (long)bc * 128;
  const float Ah = Avec[h];
  const float bias = dt_bias[h];
  float v0 = dtraw[(tok0 + lane)*64 + h] + bias;
  float v1 = dtraw[(tok0 + 64 + lane)*64 + h] + bias;
  float d0 = (v0 > 20.f) ? v0 : log1pf(expf(v0));
  float d1 = (v1 > 20.f) ? v1 : log1pf(expf(v1));
  float s0 = d0 * Ah;
  float s1 = d1 * Ah;
#pragma unroll
  for (int off = 1; off < 64; off <<= 1) {
    float t = __shfl_up(s0, off);
    if (lane >= off) s0 += t;
  }
  float tot0 = __shfl(s0, 63);
#pragma unroll
  for (int off = 1; off < 64; off <<= 1) {
    float t = __shfl_up(s1, off);
    if (lane >= off) s1 += t;
  }
  s1 += tot0;
  const size_t base = (size_t)wid * 128;
  dt_s[base + lane] = d0;
  dt_s[base + 64 + lane] = d1;
  dAcs[base + lane] = s0;
  dAcs[base + 64 + lane] = s1;
  if (lane == 63) cdec[wid] = __expf(s1);
}

// ---------------- per-chunk states: dtx^T @ (decay .* Bm) -> (64 x 128) bf16 ----------------
__global__ __launch_bounds__(256)
void states_kernel(const bf16_t* __restrict__ x, const bf16_t* __restrict__ Bm,
                   const float* __restrict__ dt_s, const float* __restrict__ dAcs,
                   bf16_t* __restrict__ states) {
  __shared__ bf16_t sDtx[8192];
  __shared__ bf16_t sBd[16384];
  __shared__ float sDt[128];
  __shared__ float sDec[128];
  const int wid = blockIdx.x;
  const int h = wid & 63;
  const int bc = wid >> 6;
  const int tid = threadIdx.x;
  const int lane = tid & 63;
  const int w = tid >> 6;
  const long tok0 = (long)bc * 128;
  const size_t dbase = (size_t)wid * 128;

  if (tid < 128) {
    sDt[tid] = dt_s[dbase + tid];
  } else {
    int j = tid - 128;
    sDec[j] = __expf(dAcs[dbase + 127] - dAcs[dbase + j]);
  }
  __syncthreads();

  {
    const int jj0 = tid >> 3;
    const int pg = (tid & 7) * 8;
#pragma unroll
    for (int t = 0; t < 4; ++t) {
      int j = t*32 + jj0;
      bf16x8 xv = *(const bf16x8*)&x[(tok0 + j)*(long)DINNER + h*64 + pg];
      float dtj = sDt[j];
      int kq = (j >> 5) * 4;
      int qe = ((j >> 3) & 3) * 16;
      int e = j & 7;
#pragma unroll
      for (int i = 0; i < 8; ++i) {
        int p = pg + i;
        sDtx[((kq + (p>>4))*64 + qe + (p&15))*8 + e] = (bf16_t)((float)xv[i]*dtj);
      }
    }
    const int jj1 = tid >> 4;
    const int ng = (tid & 15) * 8;
#pragma unroll
    for (int t = 0; t < 8; ++t) {
      int j = t*16 + jj1;
      bf16x8 bv = *(const bf16x8*)&Bm[(tok0 + j)*(long)DSTATE + ng];
      float dec = sDec[j];
      int kq = (j >> 5) * 8;
      int qe = ((j >> 3) & 3) * 16;
      int e = j & 7;
#pragma unroll
      for (int i = 0; i < 8; ++i) {
        int n = ng + i;
        sBd[((kq + (n>>4))*64 + qe + (n&15))*8 + e] = (bf16_t)((float)bv[i]*dec);
      }
    }
  }
  __syncthreads();

  f32x4 acc[4][2] = {};
#pragma unroll
  for (int kt = 0; kt < 4; ++kt) {
    bf16x8 aF[4], bF[2];
#pragma unroll
    for (int mt = 0; mt < 4; ++mt) aF[mt] = *(const bf16x8*)&sDtx[((kt*4 + mt)*64 + lane)*8];
#pragma unroll
    for (int nt = 0; nt < 2; ++nt) bF[nt] = *(const bf16x8*)&sBd[((kt*8 + w*2 + nt)*64 + lane)*8];
#pragma unroll
    for (int mt = 0; mt < 4; ++mt)
#pragma unroll
      for (int nt = 0; nt < 2; ++nt)
        acc[mt][nt] = mfma16(aF[mt], bF[nt], acc[mt][nt]);
  }

  bf16_t* S = states + (size_t)wid * (HD * DSTATE);
  const int cr = (lane >> 4) * 4;
  const int cc = lane & 15;
#pragma unroll
  for (int mt = 0; mt < 4; ++mt)
#pragma unroll
    for (int nt = 0; nt < 2; ++nt) {
      int n = (w*2 + nt)*16 + cc;
#pragma unroll
      for (int r = 0; r < 4; ++r) {
        int p = mt*16 + cr + r;
        S[(size_t)p*DSTATE + n] = (bf16_t)acc[mt][nt][r];
      }
    }
}

// ---------------- inter-chunk scan over 32 chunks (in-place: states -> prevs) ----------------
__global__ __launch_bounds__(256)
void scan_kernel(bf16_t* __restrict__ sp, const float* __restrict__ cdec) {
  const size_t gid = (size_t)blockIdx.x * 256 + threadIdx.x;
  const int n = gid & 127;
  const int p = (gid >> 7) & 63;
  const int h = (gid >> 13) & 63;
  const int b = (int)(gid >> 19);
  float prev = 0.f;
  const size_t pn = (size_t)p * 128 + n;
  for (int c = 0; c < 32; ++c) {
    const int wid = (b*32 + c)*64 + h;
    const size_t idx = (size_t)wid * 8192 + pn;
    float s = (float)sp[idx];
    sp[idx] = (bf16_t)prev;
    prev = cdec[wid] * prev + s;
  }
}

// ---------------- per-chunk Y: inter + intra + D*x (in-place over x) ----------------
__global__ __launch_bounds__(256)
void ssd_y_kernel(bf16_t* __restrict__ xy, const bf16_t* __restrict__ Bm,
                  const bf16_t* __restrict__ Cm, const bf16_t* __restrict__ prevs,
                  const float* __restrict__ dt_s, const float* __restrict__ dAcs,
                  const float* __restrict__ Dvec) {
  __shared__ bf16_t sG[16384];
  __shared__ bf16_t sDtx[8192];
  __shared__ float sDA[128];
  __shared__ float sEA[128];
  __shared__ float sDt[128];

  const int wid = blockIdx.x;
  const int h = wid & 63;
  const int bc = wid >> 6;
  const int tid = threadIdx.x;
  const int lane = tid & 63;
  const int w = tid >> 6;
  const long tok0 = (long)bc * 128;
  const size_t dbase = (size_t)wid * 128;

  if (tid < 128) {
    float v = dAcs[dbase + tid];
    sDA[tid] = v;
    sEA[tid] = __expf(v);
  } else {
    sDt[tid - 128] = dt_s[dbase + tid - 128];
  }
  __syncthreads();

  {
    const int jj0 = tid >> 3;
    const int pg = (tid & 7) * 8;
#pragma unroll
    for (int t = 0; t < 4; ++t) {
      int j = t*32 + jj0;
      bf16x8 xv = *(const bf16x8*)&xy[(tok0 + j)*(long)DINNER + h*64 + pg];
      float dtj = sDt[j];
      int kq = (j >> 5) * 4;
      int qe = ((j >> 3) & 3) * 16;
      int e = j & 7;
#pragma unroll
      for (int i = 0; i < 8; ++i) {
        int p = pg + i;
        sDtx[((kq + (p>>4))*64 + qe + (p&15))*8 + e] = (bf16_t)((float)xv[i]*dtj);
      }
    }
  }

  const int arow = (w*2)*16 + (lane & 15);
  const int koff = (lane >> 4) * 8;
  bf16x8 aCm[2][4];
#pragma unroll
  for (int mi = 0; mi < 2; ++mi)
#pragma unroll
    for (int kt = 0; kt < 4; ++kt)
      aCm[mi][kt] = *(const bf16x8*)&Cm[(tok0 + arow + mi*16)*(long)DSTATE + kt*32 + koff];

  const bf16_t* P = prevs + (size_t)wid * 8192;
  f32x4 accY[2][4] = {};
#pragma unroll
  for (int kt = 0; kt < 4; ++kt) {
    bf16x8 bP[4];
#pragma unroll
    for (int ni = 0; ni < 4; ++ni)
      bP[ni] = *(const bf16x8*)&P[(size_t)(ni*16 + (lane & 15))*DSTATE + kt*32 + koff];
#pragma unroll
    for (int mi = 0; mi < 2; ++mi)
#pragma unroll
      for (int ni = 0; ni < 4; ++ni)
        accY[mi][ni] = mfma16(aCm[mi][kt], bP[ni], accY[mi][ni]);
  }
  const int cr = (lane >> 4) * 4;
  const int cc = lane & 15;
#pragma unroll
  for (int mi = 0; mi < 2; ++mi)
#pragma unroll
    for (int r = 0; r < 4; ++r) {
      float e = sEA[(w*2 + mi)*16 + cr + r];
#pragma unroll
      for (int ni = 0; ni < 4; ++ni) accY[mi][ni][r] *= e;
    }

  f32x4 accS[2][8] = {};
#pragma unroll
  for (int kt = 0; kt < 4; ++kt) {
    bf16x8 bB[8];
#pragma unroll
    for (int nt = 0; nt < 8; ++nt)
      bB[nt] = *(const bf16x8*)&Bm[(tok0 + nt*16 + (lane & 15))*(long)DSTATE + kt*32 + koff];
#pragma unroll
    for (int mi = 0; mi < 2; ++mi)
#pragma unroll
      for (int nt = 0; nt < 8; ++nt)
        accS[mi][nt] = mfma16(aCm[mi][kt], bB[nt], accS[mi][nt]);
  }

#pragma unroll
  for (int mi = 0; mi < 2; ++mi)
#pragma unroll
    for (int nt = 0; nt < 8; ++nt)
#pragma unroll
      for (int r = 0; r < 4; ++r) {
        int i = (w*2 + mi)*16 + cr + r;
        int j = nt*16 + cc;
        float g = (i >= j) ? accS[mi][nt][r] * __expf(sDA[i] - sDA[j]) : 0.f;
        sG[(((j>>5)*8 + (i>>4))*64 + ((j>>3)&3)*16 + (i&15))*8 + (j&7)] = (bf16_t)g;
      }
  __syncthreads();

#pragma unroll
  for (int kt = 0; kt < 4; ++kt) {
    bf16x8 aG[2], bD[4];
#pragma unroll
    for (int mi = 0; mi < 2; ++mi) aG[mi] = *(const bf16x8*)&sG[((kt*8 + w*2 + mi)*64 + lane)*8];
#pragma unroll
    for (int ni = 0; ni < 4; ++ni) bD[ni] = *(const bf16x8*)&sDtx[((kt*4 + ni)*64 + lane)*8];
#pragma unroll
    for (int mi = 0; mi < 2; ++mi)
#pragma unroll
      for (int ni = 0; ni < 4; ++ni)
        accY[mi][ni] = mfma16(aG[mi], bD[ni], accY[mi][ni]);
  }

  const float Dh = Dvec[h];
#pragma unroll
  for (int mi = 0; mi < 2; ++mi)
#pragma unroll
    for (int ni = 0; ni < 4; ++ni)
#pragma unroll
      for (int r = 0; r < 4; ++r) {
        long tokr = tok0 + (w*2 + mi)*16 + cr + r;
        int p = ni*16 + cc;
        long idx = tokr * DINNER + h*64 + p;
        float xv = (float)xy[idx];
        xy[idx] = (bf16_t)(accY[mi][ni][r] + Dh * xv);
      }
}

// ---------------- gating + RMS norm ----------------
__global__ __launch_bounds__(256)
void gate_kernel(const bf16_t* __restrict__ y, const bf16_t* __restrict__ z,
                 const float* __restrict__ norm_w, bf16_t* __restrict__ yn) {
  const int tok = blockIdx.x;
  const int tid = threadIdx.x;
  const int lane = tid & 63;
  const int w = tid >> 6;
  const bf16_t* yrow = y + (size_t)tok * DINNER;
  const bf16_t* zrow = z + (size_t)tok * DINNER;
  float local[16];
  float ss = 0.f;
#pragma unroll
  for (int v = 0; v < 2; ++v) {
    int col = tid*16 + v*8;
    bf16x8 yv = *(const bf16x8*)&yrow[col];
    bf16x8 zv = *(const bf16x8*)&zrow[col];
#pragma unroll
    for (int i = 0; i < 8; ++i) {
      float zf = (float)zv[i];
      float g = zf / (1.f + __expf(-zf));
      float t = (float)yv[i] * g;
      local[v*8 + i] = t;
      ss += t*t;
    }
  }
#pragma unroll
  for (int off = 32; off > 0; off >>= 1) ss += __shfl_xor(ss, off);
  __shared__ float red[4];
  if (lane == 0) red[w] = ss;
  __syncthreads();
  float rms = rsqrtf((red[0]+red[1]+red[2]+red[3]) * (1.f/DINNER) + 1e-5f);
  bf16_t* orow = yn + (size_t)tok * DINNER;
#pragma unroll
  for (int v = 0; v < 2; ++v) {
    int col = tid*16 + v*8;
    bf16x8 o;
#pragma unroll
    for (int i = 0; i < 8; ++i) o[i] = (bf16_t)(local[v*8+i] * rms * norm_w[col+i]);
    *(bf16x8*)&orow[col] = o;
  }
}

// ---------------- launch ----------------
extern "C" void kernel_launch(void* const* d_in, const int* in_sizes, int n_in,
                              void* d_out, int out_size, void* d_ws, size_t ws_size,
                              hipStream_t stream) {
  const float* hidden  = (const float*)d_in[0];
  const float* W_in    = (const float*)d_in[1];
  const float* conv_w  = (const float*)d_in[2];
  const float* conv_b  = (const float*)d_in[3];
  const float* Avec    = (const float*)d_in[4];
  const float* Dvec    = (const float*)d_in[5];
  const float* dt_bias = (const float*)d_in[6];
  const float* norm_w  = (const float*)d_in[7];
  const float* W_out   = (const float*)d_in[8];

  char* ws = (char*)d_ws;
  size_t off = 0;
  auto take = [&](size_t bytes) -> char* {
    char* p = ws + off;
    off += (bytes + 255) & ~(size_t)255;
    return p;
  };
  bf16_t* R1    = (bf16_t*)take((size_t)NBC * NH * HD * DSTATE * 2);  // Xb -> states -> ynbuf
  bf16_t* WinT  = (bf16_t*)take((size_t)WINT_ROWS * DMODEL * 2);      // later WoutT
  bf16_t* xbc   = (bf16_t*)take((size_t)TOK * XBCN * 2);              // Xlo lives here first
  bf16_t* xconv = (bf16_t*)take((size_t)TOK * DINNER * 2);            // y in-place
  bf16_t* Bmat  = (bf16_t*)take((size_t)TOK * DSTATE * 2);
  bf16_t* Cmat  = (bf16_t*)take((size_t)TOK * DSTATE * 2);
  float*  dtraw = (float*)take((size_t)TOK * NH * 4);
  float*  dt_s  = (float*)take((size_t)TOK * NH * 4);
  float*  dAcs  = (float*)take((size_t)TOK * NH * 4);
  float*  cdec  = (float*)take((size_t)NBC * NH * 4);
  bf16_t* Wdth  = (bf16_t*)take((size_t)NH * DMODEL * 2);
  bf16_t* Wdtl  = (bf16_t*)take((size_t)NH * DMODEL * 2);
  if (off > ws_size) return;

  bf16_t* Xb      = R1;
  bf16_t* Xlo     = xbc;               // dead before xbc-gemm writes
  bf16_t* statesB = R1;
  bf16_t* ynbuf   = R1;
  bf16_t* WoutT   = WinT;
  bf16_t* zbuf    = (bf16_t*)d_out;    // z as bf16 in d_out
  float*  out     = (float*)d_out;

  cast_split_kernel<<<(TOK*DMODEL)/2048, 256, 0, stream>>>(hidden, Xb, Xlo, (size_t)TOK*DMODEL);
  wdt_split_kernel<<<DMODEL/256, 256, 0, stream>>>(W_in, Wdth, Wdtl);
  dt_mfma_kernel<<<TOK/128, 256, 0, stream>>>(Xb, Xlo, Wdth, Wdtl, dtraw);
  transpose_cast_kernel<<<dim3(WINT_ROWS/32, DMODEL/32), 256, 0, stream>>>(W_in, WinT, DMODEL, 8512, WINT_ROWS);
  // fused in-proj: cols [0,4096) -> zbuf, [4096,8448) -> xbc
  gemm256<bf16_t><<<(TOK/256)*(WINT_ROWS/256), 512, 0, stream>>>(
      Xb, WinT, zbuf, xbc, TOK, WINT_ROWS, DMODEL, DINNER, WINT_ROWS/256);
  transpose_cast_kernel<<<dim3(DMODEL/32, DINNER/32), 256, 0, stream>>>(W_out, WoutT, DINNER, DMODEL, DMODEL);
  conv_kernel<<<dim3(XBCN/256, TOK/8), 256, 0, stream>>>(xbc, conv_w, conv_b, xconv, Bmat, Cmat);
  dt_scan_kernel<<<(NBC*NH)/4, 256, 0, stream>>>(dtraw, dt_bias, Avec, dt_s, dAcs, cdec);
  states_kernel<<<NBC*NH, 256, 0, stream>>>(xconv, Bmat, dt_s, dAcs, statesB);
  scan_kernel<<<(NBC*NH*HD*DSTATE)/(32*256), 256, 0, stream>>>(statesB, cdec);
  ssd_y_kernel<<<NBC*NH, 256, 0, stream>>>(xconv, Bmat, Cmat, statesB, dt_s, dAcs, Dvec);
  gate_kernel<<<TOK, 256, 0, stream>>>(xconv, zbuf, norm_w, ynbuf);
  // out-proj
  gemm256<float><<<(TOK/256)*(DMODEL/256), 512, 0, stream>>>(
      ynbuf, WoutT, out, out, TOK, DMODEL, DINNER, DMODEL, DMODEL/256);
}

// Round 6
// 989.977 us; speedup vs baseline: 1.3301x; 1.1009x over previous
//
#include <hip/hip_runtime.h>
#include <hip/hip_bf16.h>

typedef __bf16 bf16_t;
typedef bf16_t bf16x8 __attribute__((ext_vector_type(8)));
typedef float f32x4 __attribute__((ext_vector_type(4)));

#define TOK 8192          // B*S
#define DMODEL 2048
#define DINNER 4096
#define XBCN 4352         // conv dim = 34*128
#define DSTATE 128
#define NH 64
#define HD 64
#define NBC 64            // B * (S/CHUNK) = 2*32
#define WINT_ROWS 8448    // z (4096) + xbc (4352)

// async global->LDS, 16B per lane, LDS dest = wave-uniform base + lane*16
__device__ __forceinline__ void gld16(const bf16_t* g, bf16_t* l) {
  __builtin_amdgcn_global_load_lds((const __attribute__((address_space(1))) void*)g,
                                   (__attribute__((address_space(3))) void*)l, 16, 0, 0);
}

__device__ __forceinline__ f32x4 mfma16(bf16x8 a, bf16x8 b, f32x4 c) {
  return __builtin_amdgcn_mfma_f32_16x16x32_bf16(a, b, c, 0, 0, 0);
}

// opaque LDS read: compiler cannot link it to global_load_lds's LDS writes,
// so it emits NO vmcnt waits for it; we do our own counted vmcnt + lgkmcnt.
__device__ __forceinline__ bf16x8 ldsr(unsigned addr) {
  f32x4 r;
  asm volatile("ds_read_b128 %0, %1" : "=v"(r) : "v"(addr));
  return __builtin_bit_cast(bf16x8, r);
}

// ---------------- utility kernels ----------------

// hidden f32 -> hi (bf16) + lo (bf16 residual)
__global__ __launch_bounds__(256)
void cast_split_kernel(const float* __restrict__ in, bf16_t* __restrict__ hi,
                       bf16_t* __restrict__ lo, size_t n) {
  size_t i = ((size_t)blockIdx.x * 256 + threadIdx.x) * 8;
  if (i + 8 > n) return;
  float4 a = *(const float4*)(in + i);
  float4 b = *(const float4*)(in + i + 4);
  float v[8] = {a.x,a.y,a.z,a.w,b.x,b.y,b.z,b.w};
  bf16x8 h, l;
#pragma unroll
  for (int j = 0; j < 8; ++j) {
    h[j] = (bf16_t)v[j];
    l[j] = (bf16_t)(v[j] - (float)h[j]);
  }
  *(bf16x8*)(hi + i) = h;
  *(bf16x8*)(lo + i) = l;
}

// in: R x C f32 row-major -> out: outRows x R bf16 (out[c][r] = in[r][c])
__global__ __launch_bounds__(256)
void transpose_cast_kernel(const float* __restrict__ in, bf16_t* __restrict__ out,
                           int R, int C, int outRows) {
  __shared__ float tile[32][33];
  const int c0 = blockIdx.x * 32;
  const int r0 = blockIdx.y * 32;
  const int tx = threadIdx.x & 31;
  const int ty = threadIdx.x >> 5;
#pragma unroll
  for (int k = 0; k < 4; ++k) {
    int r = r0 + ty + k*8;
    int c = c0 + tx;
    tile[ty + k*8][tx] = (c < C) ? in[(size_t)r * C + c] : 0.f;
  }
  __syncthreads();
#pragma unroll
  for (int k = 0; k < 4; ++k) {
    int oc = c0 + ty + k*8;
    int orr = r0 + tx;
    out[(size_t)oc * R + orr] = (bf16_t)tile[tx][ty + k*8];
  }
}

// W_in dt columns -> Whi/Wlo [64][2048] bf16 split
__global__ __launch_bounds__(256)
void wdt_split_kernel(const float* __restrict__ Win, bf16_t* __restrict__ Whi,
                      bf16_t* __restrict__ Wlo) {
  const int h = threadIdx.x & 63;
  const int k0 = blockIdx.x * 256 + (threadIdx.x >> 6) * 64;
#pragma unroll 4
  for (int i = 0; i < 64; ++i) {
    int k = k0 + i;
    float v = Win[(size_t)k * 8512 + 8448 + h];
    bf16_t hv = (bf16_t)v;
    Whi[(size_t)h * DMODEL + k] = hv;
    Wlo[(size_t)h * DMODEL + k] = (bf16_t)(v - (float)hv);
  }
}

// ---------------- 256x256 8-phase GEMM: A(MxK) @ B(NxK)^T -> C(MxN) ----------------
// 512 threads = 8 waves (2M x 4N), BK=64, 128KB LDS double-buffered.
// LDS in MFMA-fragment order (pre-swizzled global source, linear LDS dest).
// Opaque asm ds_read_b128 + counted vmcnt (never 0 in steady loop) + setprio.
// XCD chunk = 4 tile-rows, iterated column-major for L2 reuse.
// Column split: cols [0,splitN) -> C0 (ld=splitN), [splitN,N) -> C1.
template <typename OutT>
__global__ __launch_bounds__(512, 2)
void gemm256(const bf16_t* __restrict__ A, const bf16_t* __restrict__ B,
             OutT* __restrict__ C0, OutT* __restrict__ C1,
             long M, long N, long K, long splitN, int gridX) {
  __shared__ bf16_t sA[2][2][8192];   // [buf][half][(f*2+s)*512 + lane*8 + e]
  __shared__ bf16_t sB[2][2][8192];
  const int tid = threadIdx.x;
  const int lane = tid & 63;
  const int wid = tid >> 6;          // 0..7
  const int wr = wid >> 2;           // 0..1  (M)
  const int wc = wid & 3;            // 0..3  (N)

  // XCD chunk (contiguous, rows 4x..4x+3) iterated column-major.
  // requires gridDim.x == 8 * 4 * gridX (holds for both call sites).
  const int x = blockIdx.x & 7;
  const int q = blockIdx.x >> 3;     // 0..cpx-1
  const long bm = (long)(x * 4 + (q & 3)) * 256;
  const long bn = (long)(q >> 2) * 256;

  // staging source mapping (fragment order): wave wid stages its slice
  const int srow = (wid >> 1) * 16 + (lane & 15);      // + c*64 within 128-row half
  const int skof = (wid & 1) * 32 + (lane >> 4) * 8;   // k within 64-k tile
  const bf16_t* Abase = A + (bm + srow) * K + skof;
  const bf16_t* Bbase = B + (bn + srow) * K + skof;

  auto stageA = [&](int buf, int h, long kt) {
    const bf16_t* s = Abase + (long)h * 128 * K + kt;
    gld16(s,          &sA[buf][h][wid * 512]);
    gld16(s + 64 * K, &sA[buf][h][4096 + wid * 512]);
  };
  auto stageB = [&](int buf, int h, long kt) {
    const bf16_t* s = Bbase + (long)h * 128 * K + kt;
    gld16(s,          &sB[buf][h][wid * 512]);
    gld16(s + 64 * K, &sB[buf][h][4096 + wid * 512]);
  };

  // LDS byte-address bases for opaque reads
  const unsigned sAb = (unsigned)(uintptr_t)(__attribute__((address_space(3))) void*)&sA[0][0][0]
                       + (unsigned)lane * 16 + (unsigned)wr * 8192;
  const unsigned sBb = (unsigned)(uintptr_t)(__attribute__((address_space(3))) void*)&sB[0][0][0]
                       + (unsigned)lane * 16 + (unsigned)wc * 4096;

  // prologue: stage tile 0 in order A0,B0,B1,A1 (8 loads)
  stageA(0, 0, 0); stageB(0, 0, 0); stageB(0, 1, 0); stageA(0, 1, 0);

  f32x4 acc[8][4] = {};
  bf16x8 a[4][2], b[2][2];
  int cur = 0;
  const int NT = (int)(K >> 6);

  for (int t = 0; t < NT; ++t) {
    const bool fin = (t == NT - 1);
    const long ktn = (long)(t + 1) * 64;
    const unsigned ab0 = sAb + (unsigned)cur * 32768;
    const unsigned bb0 = sBb + (unsigned)cur * 32768;

    // ---- phase 0: A-h0 x B-h0 ----
    asm volatile("s_waitcnt vmcnt(4)\n\ts_barrier" ::: "memory");
    if (!fin) stageA(cur ^ 1, 0, ktn);
#pragma unroll
    for (int mi = 0; mi < 4; ++mi) {
      a[mi][0] = ldsr(ab0 + (mi*2+0)*1024);
      a[mi][1] = ldsr(ab0 + (mi*2+1)*1024);
    }
#pragma unroll
    for (int ni = 0; ni < 2; ++ni) {
      b[ni][0] = ldsr(bb0 + (ni*2+0)*1024);
      b[ni][1] = ldsr(bb0 + (ni*2+1)*1024);
    }
    asm volatile("s_waitcnt lgkmcnt(0)" ::: "memory");
    __builtin_amdgcn_sched_barrier(0);
    __builtin_amdgcn_s_setprio(1);
#pragma unroll
    for (int mi = 0; mi < 4; ++mi)
#pragma unroll
      for (int ni = 0; ni < 2; ++ni) {
        acc[mi][ni] = mfma16(a[mi][0], b[ni][0], acc[mi][ni]);
        acc[mi][ni] = mfma16(a[mi][1], b[ni][1], acc[mi][ni]);
      }
    __builtin_amdgcn_s_setprio(0);
    __builtin_amdgcn_sched_barrier(0);

    // ---- phase 1: A-h0 x B-h1 ----
    if (!fin) asm volatile("s_waitcnt vmcnt(4)\n\ts_barrier" ::: "memory");
    else      asm volatile("s_waitcnt vmcnt(2)\n\ts_barrier" ::: "memory");
    if (!fin) stageB(cur ^ 1, 0, ktn);
#pragma unroll
    for (int ni = 0; ni < 2; ++ni) {
      b[ni][0] = ldsr(bb0 + 16384 + (ni*2+0)*1024);
      b[ni][1] = ldsr(bb0 + 16384 + (ni*2+1)*1024);
    }
    asm volatile("s_waitcnt lgkmcnt(0)" ::: "memory");
    __builtin_amdgcn_sched_barrier(0);
    __builtin_amdgcn_s_setprio(1);
#pragma unroll
    for (int mi = 0; mi < 4; ++mi)
#pragma unroll
      for (int ni = 0; ni < 2; ++ni) {
        acc[mi][2 + ni] = mfma16(a[mi][0], b[ni][0], acc[mi][2 + ni]);
        acc[mi][2 + ni] = mfma16(a[mi][1], b[ni][1], acc[mi][2 + ni]);
      }
    __builtin_amdgcn_s_setprio(0);
    __builtin_amdgcn_sched_barrier(0);

    // ---- phase 2: A-h1 x B-h1 ----
    if (!fin) asm volatile("s_waitcnt vmcnt(4)\n\ts_barrier" ::: "memory");
    else      asm volatile("s_waitcnt vmcnt(0)\n\ts_barrier" ::: "memory");
    if (!fin) stageB(cur ^ 1, 1, ktn);
#pragma unroll
    for (int mi = 0; mi < 4; ++mi) {
      a[mi][0] = ldsr(ab0 + 16384 + (mi*2+0)*1024);
      a[mi][1] = ldsr(ab0 + 16384 + (mi*2+1)*1024);
    }
    asm volatile("s_waitcnt lgkmcnt(0)" ::: "memory");
    __builtin_amdgcn_sched_barrier(0);
    __builtin_amdgcn_s_setprio(1);
#pragma unroll
    for (int mi = 0; mi < 4; ++mi)
#pragma unroll
      for (int ni = 0; ni < 2; ++ni) {
        acc[4 + mi][2 + ni] = mfma16(a[mi][0], b[ni][0], acc[4 + mi][2 + ni]);
        acc[4 + mi][2 + ni] = mfma16(a[mi][1], b[ni][1], acc[4 + mi][2 + ni]);
      }
    __builtin_amdgcn_s_setprio(0);
    __builtin_amdgcn_sched_barrier(0);

    // ---- phase 3: A-h1 x B-h0 (re-read B0 from LDS; no vmcnt needed) ----
    asm volatile("s_barrier" ::: "memory");
    if (!fin) stageA(cur ^ 1, 1, ktn);
#pragma unroll
    for (int ni = 0; ni < 2; ++ni) {
      b[ni][0] = ldsr(bb0 + (ni*2+0)*1024);
      b[ni][1] = ldsr(bb0 + (ni*2+1)*1024);
    }
    asm volatile("s_waitcnt lgkmcnt(0)" ::: "memory");
    __builtin_amdgcn_sched_barrier(0);
    __builtin_amdgcn_s_setprio(1);
#pragma unroll
    for (int mi = 0; mi < 4; ++mi)
#pragma unroll
      for (int ni = 0; ni < 2; ++ni) {
        acc[4 + mi][ni] = mfma16(a[mi][0], b[ni][0], acc[4 + mi][ni]);
        acc[4 + mi][ni] = mfma16(a[mi][1], b[ni][1], acc[4 + mi][ni]);
      }
    __builtin_amdgcn_s_setprio(0);
    __builtin_amdgcn_sched_barrier(0);
    cur ^= 1;
  }

  // epilogue
  const int cr = (lane >> 4) * 4;
  const int cc = lane & 15;
  OutT* Cb;
  long col0, ldc;
  if (bn < splitN) { Cb = C0; col0 = bn; ldc = splitN; }
  else             { Cb = C1; col0 = bn - splitN; ldc = N - splitN; }
#pragma unroll
  for (int mi = 0; mi < 8; ++mi) {
    long row = bm + (mi >> 2) * 128 + wr * 64 + (mi & 3) * 16 + cr;
#pragma unroll
    for (int ni = 0; ni < 4; ++ni) {
      long col = col0 + (ni >> 1) * 128 + wc * 32 + (ni & 1) * 16 + cc;
      OutT* p = Cb + row * ldc + col;
#pragma unroll
      for (int r = 0; r < 4; ++r) p[(long)r * ldc] = (OutT)acc[mi][ni][r];
    }
  }
}

// ---------------- dt via split-bf16 MFMA: hi*hi + hi*lo + lo*hi ----------------
__global__ __launch_bounds__(256)
void dt_mfma_kernel(const bf16_t* __restrict__ Ahi, const bf16_t* __restrict__ Alo,
                    const bf16_t* __restrict__ Whi, const bf16_t* __restrict__ Wlo,
                    float* __restrict__ dtraw) {
  __shared__ bf16_t sAh[4096], sAl[4096], sBh[2048], sBl[2048];
  const int tid = threadIdx.x;
  const int lane = tid & 63;
  const int w = tid >> 6;
  const long bm = (long)blockIdx.x * 128;
  const int rlo = lane & 15;
  const int kq = lane >> 4;

  const bf16_t* Ah0 = Ahi + (bm + 2*w*16 + rlo) * (long)DMODEL + kq*8;
  const bf16_t* Ah1 = Ah0 + 16*(long)DMODEL;
  const bf16_t* Al0 = Alo + (bm + 2*w*16 + rlo) * (long)DMODEL + kq*8;
  const bf16_t* Al1 = Al0 + 16*(long)DMODEL;
  const bf16_t* Bh0 = Whi + (w*16 + rlo) * (long)DMODEL + kq*8;
  const bf16_t* Bl0 = Wlo + (w*16 + rlo) * (long)DMODEL + kq*8;

  f32x4 acc[2][4] = {};

  for (int kt = 0; kt < DMODEL; kt += 32) {
    __syncthreads();
    gld16(Ah0 + kt, &sAh[(2*w)*512]);
    gld16(Ah1 + kt, &sAh[(2*w+1)*512]);
    gld16(Al0 + kt, &sAl[(2*w)*512]);
    gld16(Al1 + kt, &sAl[(2*w+1)*512]);
    gld16(Bh0 + kt, &sBh[w*512]);
    gld16(Bl0 + kt, &sBl[w*512]);
    __syncthreads();
    bf16x8 ah[2], al[2], bh[4], bl[4];
#pragma unroll
    for (int i = 0; i < 2; ++i) {
      ah[i] = *(const bf16x8*)&sAh[((2*w + i)*64 + lane)*8];
      al[i] = *(const bf16x8*)&sAl[((2*w + i)*64 + lane)*8];
    }
#pragma unroll
    for (int n = 0; n < 4; ++n) {
      bh[n] = *(const bf16x8*)&sBh[(n*64 + lane)*8];
      bl[n] = *(const bf16x8*)&sBl[(n*64 + lane)*8];
    }
#pragma unroll
    for (int mi = 0; mi < 2; ++mi)
#pragma unroll
      for (int n = 0; n < 4; ++n) {
        acc[mi][n] = mfma16(ah[mi], bh[n], acc[mi][n]);
        acc[mi][n] = mfma16(ah[mi], bl[n], acc[mi][n]);
        acc[mi][n] = mfma16(al[mi], bh[n], acc[mi][n]);
      }
  }

  const int cr = (lane >> 4) * 4;
  const int cc = lane & 15;
#pragma unroll
  for (int mi = 0; mi < 2; ++mi)
#pragma unroll
    for (int n = 0; n < 4; ++n)
#pragma unroll
      for (int r = 0; r < 4; ++r)
        dtraw[(bm + 2*w*16 + mi*16 + cr + r) * 64 + n*16 + cc] = acc[mi][n][r];
}

// ---------------- causal conv1d (K=4) + SiLU, split x/B/C ----------------
__global__ __launch_bounds__(256)
void conv_kernel(const bf16_t* __restrict__ xbc, const float* __restrict__ cw,
                 const float* __restrict__ cb, bf16_t* __restrict__ xo,
                 bf16_t* __restrict__ Bout, bf16_t* __restrict__ Cout) {
  const int c = blockIdx.x * 256 + threadIdx.x;
  const int t0 = blockIdx.y * 8;
  const int bstart = (t0 >> 12) << 12;
  const float w0 = cw[c*4+0], w1 = cw[c*4+1], w2 = cw[c*4+2], w3 = cw[c*4+3];
  const float bias = cb[c];
  float in[11];
#pragma unroll
  for (int k = 0; k < 11; ++k) {
    int t = t0 - 3 + k;
    in[k] = (t >= bstart) ? (float)xbc[(size_t)t * XBCN + c] : 0.f;
  }
#pragma unroll
  for (int i = 0; i < 8; ++i) {
    float v = bias + w0*in[i] + w1*in[i+1] + w2*in[i+2] + w3*in[i+3];
    float s = v / (1.f + __expf(-v));
    int t = t0 + i;
    bf16_t o = (bf16_t)s;
    if (c < DINNER)           xo[(size_t)t * DINNER + c] = o;
    else if (c < DINNER+128)  Bout[(size_t)t * DSTATE + (c - DINNER)] = o;
    else                      Cout[(size_t)t * DSTATE + (c - DINNER - 128)] = o;
  }
}

// ---------------- softplus(dt)+cumsum(dA) per (b,chunk,head) ----------------
__global__ __launch_bounds__(256)
void dt_scan_kernel(const float* __restrict__ dtraw, const float* __restrict__ dt_bias,
                    const float* __restrict__ Avec, float* __restrict__ dt_s,
                    float* __restrict__ dAcs, float* __restrict__ cdec) {
  const int wid = blockIdx.x * 4 + (threadIdx.x >> 6);
  const int lane = threadIdx.x & 63;
  const int h = wid & 63;
  const int bc = wid >> 6;
  const long tok0 = (long)bc * 128;
  const float Ah = Avec[h];
  const float bias = dt_bias[h];
  float v0 = dtraw[(tok0 + lane)*64 + h] + bias;
  float v1 = dtraw[(tok0 + 64 + lane)*64 + h] + bias;
  float d0 = (v0 > 20.f) ? v0 : log1pf(expf(v0));
  float d1 = (v1 > 20.f) ? v1 : log1pf(expf(v1));
  float s0 = d0 * Ah;
  float s1 = d1 * Ah;
#pragma unroll
  for (int off = 1; off < 64; off <<= 1) {
    float t = __shfl_up(s0, off);
    if (lane >= off) s0 += t;
  }
  float tot0 = __shfl(s0, 63);
#pragma unroll
  for (int off = 1; off < 64; off <<= 1) {
    float t = __shfl_up(s1, off);
    if (lane >= off) s1 += t;
  }
  s1 += tot0;
  const size_t base = (size_t)wid * 128;
  dt_s[base + lane] = d0;
  dt_s[base + 64 + lane] = d1;
  dAcs[base + lane] = s0;
  dAcs[base + 64 + lane] = s1;
  if (lane == 63) cdec[wid] = __expf(s1);
}

// ---------------- per-chunk states: dtx^T @ (decay .* Bm) -> (64 x 128) bf16 ----------------
__global__ __launch_bounds__(256)
void states_kernel(const bf16_t* __restrict__ x, const bf16_t* __restrict__ Bm,
                   const float* __restrict__ dt_s, const float* __restrict__ dAcs,
                   bf16_t* __restrict__ states) {
  __shared__ bf16_t sDtx[8192];
  __shared__ bf16_t sBd[16384];
  __shared__ float sDt[128];
  __shared__ float sDec[128];
  const int wid = blockIdx.x;
  const int h = wid & 63;
  const int bc = wid >> 6;
  const int tid = threadIdx.x;
  const int lane = tid & 63;
  const int w = tid >> 6;
  const long tok0 = (long)bc * 128;
  const size_t dbase = (size_t)wid * 128;

  if (tid < 128) {
    sDt[tid] = dt_s[dbase + tid];
  } else {
    int j = tid - 128;
    sDec[j] = __expf(dAcs[dbase + 127] - dAcs[dbase + j]);
  }
  __syncthreads();

  {
    const int jj0 = tid >> 3;
    const int pg = (tid & 7) * 8;
#pragma unroll
    for (int t = 0; t < 4; ++t) {
      int j = t*32 + jj0;
      bf16x8 xv = *(const bf16x8*)&x[(tok0 + j)*(long)DINNER + h*64 + pg];
      float dtj = sDt[j];
      int kq = (j >> 5) * 4;
      int qe = ((j >> 3) & 3) * 16;
      int e = j & 7;
#pragma unroll
      for (int i = 0; i < 8; ++i) {
        int p = pg + i;
        sDtx[((kq + (p>>4))*64 + qe + (p&15))*8 + e] = (bf16_t)((float)xv[i]*dtj);
      }
    }
    const int jj1 = tid >> 4;
    const int ng = (tid & 15) * 8;
#pragma unroll
    for (int t = 0; t < 8; ++t) {
      int j = t*16 + jj1;
      bf16x8 bv = *(const bf16x8*)&Bm[(tok0 + j)*(long)DSTATE + ng];
      float dec = sDec[j];
      int kq = (j >> 5) * 8;
      int qe = ((j >> 3) & 3) * 16;
      int e = j & 7;
#pragma unroll
      for (int i = 0; i < 8; ++i) {
        int n = ng + i;
        sBd[((kq + (n>>4))*64 + qe + (n&15))*8 + e] = (bf16_t)((float)bv[i]*dec);
      }
    }
  }
  __syncthreads();

  f32x4 acc[4][2] = {};
#pragma unroll
  for (int kt = 0; kt < 4; ++kt) {
    bf16x8 aF[4], bF[2];
#pragma unroll
    for (int mt = 0; mt < 4; ++mt) aF[mt] = *(const bf16x8*)&sDtx[((kt*4 + mt)*64 + lane)*8];
#pragma unroll
    for (int nt = 0; nt < 2; ++nt) bF[nt] = *(const bf16x8*)&sBd[((kt*8 + w*2 + nt)*64 + lane)*8];
#pragma unroll
    for (int mt = 0; mt < 4; ++mt)
#pragma unroll
      for (int nt = 0; nt < 2; ++nt)
        acc[mt][nt] = mfma16(aF[mt], bF[nt], acc[mt][nt]);
  }

  bf16_t* S = states + (size_t)wid * (HD * DSTATE);
  const int cr = (lane >> 4) * 4;
  const int cc = lane & 15;
#pragma unroll
  for (int mt = 0; mt < 4; ++mt)
#pragma unroll
    for (int nt = 0; nt < 2; ++nt) {
      int n = (w*2 + nt)*16 + cc;
#pragma unroll
      for (int r = 0; r < 4; ++r) {
        int p = mt*16 + cr + r;
        S[(size_t)p*DSTATE + n] = (bf16_t)acc[mt][nt][r];
      }
    }
}

// ---------------- inter-chunk scan over 32 chunks (in-place: states -> prevs) ----------------
__global__ __launch_bounds__(256)
void scan_kernel(bf16_t* __restrict__ sp, const float* __restrict__ cdec) {
  const size_t gid = (size_t)blockIdx.x * 256 + threadIdx.x;
  const int n = gid & 127;
  const int p = (gid >> 7) & 63;
  const int h = (gid >> 13) & 63;
  const int b = (int)(gid >> 19);
  float prev = 0.f;
  const size_t pn = (size_t)p * 128 + n;
  for (int c = 0; c < 32; ++c) {
    const int wid = (b*32 + c)*64 + h;
    const size_t idx = (size_t)wid * 8192 + pn;
    float s = (float)sp[idx];
    sp[idx] = (bf16_t)prev;
    prev = cdec[wid] * prev + s;
  }
}

// ---------------- per-chunk Y: inter + intra + D*x (in-place over x) ----------------
__global__ __launch_bounds__(256)
void ssd_y_kernel(bf16_t* __restrict__ xy, const bf16_t* __restrict__ Bm,
                  const bf16_t* __restrict__ Cm, const bf16_t* __restrict__ prevs,
                  const float* __restrict__ dt_s, const float* __restrict__ dAcs,
                  const float* __restrict__ Dvec) {
  __shared__ bf16_t sG[16384];
  __shared__ bf16_t sDtx[8192];
  __shared__ float sDA[128];
  __shared__ float sEA[128];
  __shared__ float sDt[128];

  const int wid = blockIdx.x;
  const int h = wid & 63;
  const int bc = wid >> 6;
  const int tid = threadIdx.x;
  const int lane = tid & 63;
  const int w = tid >> 6;
  const long tok0 = (long)bc * 128;
  const size_t dbase = (size_t)wid * 128;

  if (tid < 128) {
    float v = dAcs[dbase + tid];
    sDA[tid] = v;
    sEA[tid] = __expf(v);
  } else {
    sDt[tid - 128] = dt_s[dbase + tid - 128];
  }
  __syncthreads();

  {
    const int jj0 = tid >> 3;
    const int pg = (tid & 7) * 8;
#pragma unroll
    for (int t = 0; t < 4; ++t) {
      int j = t*32 + jj0;
      bf16x8 xv = *(const bf16x8*)&xy[(tok0 + j)*(long)DINNER + h*64 + pg];
      float dtj = sDt[j];
      int kq = (j >> 5) * 4;
      int qe = ((j >> 3) & 3) * 16;
      int e = j & 7;
#pragma unroll
      for (int i = 0; i < 8; ++i) {
        int p = pg + i;
        sDtx[((kq + (p>>4))*64 + qe + (p&15))*8 + e] = (bf16_t)((float)xv[i]*dtj);
      }
    }
  }

  const int arow = (w*2)*16 + (lane & 15);
  const int koff = (lane >> 4) * 8;
  bf16x8 aCm[2][4];
#pragma unroll
  for (int mi = 0; mi < 2; ++mi)
#pragma unroll
    for (int kt = 0; kt < 4; ++kt)
      aCm[mi][kt] = *(const bf16x8*)&Cm[(tok0 + arow + mi*16)*(long)DSTATE + kt*32 + koff];

  const bf16_t* P = prevs + (size_t)wid * 8192;
  f32x4 accY[2][4] = {};
#pragma unroll
  for (int kt = 0; kt < 4; ++kt) {
    bf16x8 bP[4];
#pragma unroll
    for (int ni = 0; ni < 4; ++ni)
      bP[ni] = *(const bf16x8*)&P[(size_t)(ni*16 + (lane & 15))*DSTATE + kt*32 + koff];
#pragma unroll
    for (int mi = 0; mi < 2; ++mi)
#pragma unroll
      for (int ni = 0; ni < 4; ++ni)
        accY[mi][ni] = mfma16(aCm[mi][kt], bP[ni], accY[mi][ni]);
  }
  const int cr = (lane >> 4) * 4;
  const int cc = lane & 15;
#pragma unroll
  for (int mi = 0; mi < 2; ++mi)
#pragma unroll
    for (int r = 0; r < 4; ++r) {
      float e = sEA[(w*2 + mi)*16 + cr + r];
#pragma unroll
      for (int ni = 0; ni < 4; ++ni) accY[mi][ni][r] *= e;
    }

  f32x4 accS[2][8] = {};
#pragma unroll
  for (int kt = 0; kt < 4; ++kt) {
    bf16x8 bB[8];
#pragma unroll
    for (int nt = 0; nt < 8; ++nt)
      bB[nt] = *(const bf16x8*)&Bm[(tok0 + nt*16 + (lane & 15))*(long)DSTATE + kt*32 + koff];
#pragma unroll
    for (int mi = 0; mi < 2; ++mi)
#pragma unroll
      for (int nt = 0; nt < 8; ++nt)
        accS[mi][nt] = mfma16(aCm[mi][kt], bB[nt], accS[mi][nt]);
  }

#pragma unroll
  for (int mi = 0; mi < 2; ++mi)
#pragma unroll
    for (int nt = 0; nt < 8; ++nt)
#pragma unroll
      for (int r = 0; r < 4; ++r) {
        int i = (w*2 + mi)*16 + cr + r;
        int j = nt*16 + cc;
        float g = (i >= j) ? accS[mi][nt][r] * __expf(sDA[i] - sDA[j]) : 0.f;
        sG[(((j>>5)*8 + (i>>4))*64 + ((j>>3)&3)*16 + (i&15))*8 + (j&7)] = (bf16_t)g;
      }
  __syncthreads();

#pragma unroll
  for (int kt = 0; kt < 4; ++kt) {
    bf16x8 aG[2], bD[4];
#pragma unroll
    for (int mi = 0; mi < 2; ++mi) aG[mi] = *(const bf16x8*)&sG[((kt*8 + w*2 + mi)*64 + lane)*8];
#pragma unroll
    for (int ni = 0; ni < 4; ++ni) bD[ni] = *(const bf16x8*)&sDtx[((kt*4 + ni)*64 + lane)*8];
#pragma unroll
    for (int mi = 0; mi < 2; ++mi)
#pragma unroll
      for (int ni = 0; ni < 4; ++ni)
        accY[mi][ni] = mfma16(aG[mi], bD[ni], accY[mi][ni]);
  }

  const float Dh = Dvec[h];
#pragma unroll
  for (int mi = 0; mi < 2; ++mi)
#pragma unroll
    for (int ni = 0; ni < 4; ++ni)
#pragma unroll
      for (int r = 0; r < 4; ++r) {
        long tokr = tok0 + (w*2 + mi)*16 + cr + r;
        int p = ni*16 + cc;
        long idx = tokr * DINNER + h*64 + p;
        float xv = (float)xy[idx];
        xy[idx] = (bf16_t)(accY[mi][ni][r] + Dh * xv);
      }
}

// ---------------- gating + RMS norm ----------------
__global__ __launch_bounds__(256)
void gate_kernel(const bf16_t* __restrict__ y, const bf16_t* __restrict__ z,
                 const float* __restrict__ norm_w, bf16_t* __restrict__ yn) {
  const int tok = blockIdx.x;
  const int tid = threadIdx.x;
  const int lane = tid & 63;
  const int w = tid >> 6;
  const bf16_t* yrow = y + (size_t)tok * DINNER;
  const bf16_t* zrow = z + (size_t)tok * DINNER;
  float local[16];
  float ss = 0.f;
#pragma unroll
  for (int v = 0; v < 2; ++v) {
    int col = tid*16 + v*8;
    bf16x8 yv = *(const bf16x8*)&yrow[col];
    bf16x8 zv = *(const bf16x8*)&zrow[col];
#pragma unroll
    for (int i = 0; i < 8; ++i) {
      float zf = (float)zv[i];
      float g = zf / (1.f + __expf(-zf));
      float t = (float)yv[i] * g;
      local[v*8 + i] = t;
      ss += t*t;
    }
  }
#pragma unroll
  for (int off = 32; off > 0; off >>= 1) ss += __shfl_xor(ss, off);
  __shared__ float red[4];
  if (lane == 0) red[w] = ss;
  __syncthreads();
  float rms = rsqrtf((red[0]+red[1]+red[2]+red[3]) * (1.f/DINNER) + 1e-5f);
  bf16_t* orow = yn + (size_t)tok * DINNER;
#pragma unroll
  for (int v = 0; v < 2; ++v) {
    int col = tid*16 + v*8;
    bf16x8 o;
#pragma unroll
    for (int i = 0; i < 8; ++i) o[i] = (bf16_t)(local[v*8+i] * rms * norm_w[col+i]);
    *(bf16x8*)&orow[col] = o;
  }
}

// ---------------- launch ----------------
extern "C" void kernel_launch(void* const* d_in, const int* in_sizes, int n_in,
                              void* d_out, int out_size, void* d_ws, size_t ws_size,
                              hipStream_t stream) {
  const float* hidden  = (const float*)d_in[0];
  const float* W_in    = (const float*)d_in[1];
  const float* conv_w  = (const float*)d_in[2];
  const float* conv_b  = (const float*)d_in[3];
  const float* Avec    = (const float*)d_in[4];
  const float* Dvec    = (const float*)d_in[5];
  const float* dt_bias = (const float*)d_in[6];
  const float* norm_w  = (const float*)d_in[7];
  const float* W_out   = (const float*)d_in[8];

  char* ws = (char*)d_ws;
  size_t off = 0;
  auto take = [&](size_t bytes) -> char* {
    char* p = ws + off;
    off += (bytes + 255) & ~(size_t)255;
    return p;
  };
  bf16_t* R1    = (bf16_t*)take((size_t)NBC * NH * HD * DSTATE * 2);  // Xb -> states -> ynbuf
  bf16_t* WinT  = (bf16_t*)take((size_t)WINT_ROWS * DMODEL * 2);      // later WoutT
  bf16_t* xbc   = (bf16_t*)take((size_t)TOK * XBCN * 2);              // Xlo lives here first
  bf16_t* xconv = (bf16_t*)take((size_t)TOK * DINNER * 2);            // y in-place
  bf16_t* Bmat  = (bf16_t*)take((size_t)TOK * DSTATE * 2);
  bf16_t* Cmat  = (bf16_t*)take((size_t)TOK * DSTATE * 2);
  float*  dtraw = (float*)take((size_t)TOK * NH * 4);
  float*  dt_s  = (float*)take((size_t)TOK * NH * 4);
  float*  dAcs  = (float*)take((size_t)TOK * NH * 4);
  float*  cdec  = (float*)take((size_t)NBC * NH * 4);
  bf16_t* Wdth  = (bf16_t*)take((size_t)NH * DMODEL * 2);
  bf16_t* Wdtl  = (bf16_t*)take((size_t)NH * DMODEL * 2);
  if (off > ws_size) return;

  bf16_t* Xb      = R1;
  bf16_t* Xlo     = xbc;               // dead before xbc-gemm writes
  bf16_t* statesB = R1;
  bf16_t* ynbuf   = R1;
  bf16_t* WoutT   = WinT;
  bf16_t* zbuf    = (bf16_t*)d_out;    // z as bf16 in d_out
  float*  out     = (float*)d_out;

  cast_split_kernel<<<(TOK*DMODEL)/2048, 256, 0, stream>>>(hidden, Xb, Xlo, (size_t)TOK*DMODEL);
  wdt_split_kernel<<<DMODEL/256, 256, 0, stream>>>(W_in, Wdth, Wdtl);
  dt_mfma_kernel<<<TOK/128, 256, 0, stream>>>(Xb, Xlo, Wdth, Wdtl, dtraw);
  transpose_cast_kernel<<<dim3(WINT_ROWS/32, DMODEL/32), 256, 0, stream>>>(W_in, WinT, DMODEL, 8512, WINT_ROWS);
  // fused in-proj: cols [0,4096) -> zbuf, [4096,8448) -> xbc
  gemm256<bf16_t><<<(TOK/256)*(WINT_ROWS/256), 512, 0, stream>>>(
      Xb, WinT, zbuf, xbc, TOK, WINT_ROWS, DMODEL, DINNER, WINT_ROWS/256);
  transpose_cast_kernel<<<dim3(DMODEL/32, DINNER/32), 256, 0, stream>>>(W_out, WoutT, DINNER, DMODEL, DMODEL);
  conv_kernel<<<dim3(XBCN/256, TOK/8), 256, 0, stream>>>(xbc, conv_w, conv_b, xconv, Bmat, Cmat);
  dt_scan_kernel<<<(NBC*NH)/4, 256, 0, stream>>>(dtraw, dt_bias, Avec, dt_s, dAcs, cdec);
  states_kernel<<<NBC*NH, 256, 0, stream>>>(xconv, Bmat, dt_s, dAcs, statesB);
  scan_kernel<<<(NBC*NH*HD*DSTATE)/(32*256), 256, 0, stream>>>(statesB, cdec);
  ssd_y_kernel<<<NBC*NH, 256, 0, stream>>>(xconv, Bmat, Cmat, statesB, dt_s, dAcs, Dvec);
  gate_kernel<<<TOK, 256, 0, stream>>>(xconv, zbuf, norm_w, ynbuf);
  // out-proj
  gemm256<float><<<(TOK/256)*(DMODEL/256), 512, 0, stream>>>(
      ynbuf, WoutT, out, out, TOK, DMODEL, DINNER, DMODEL, DMODEL/256);
}